// Round 9
// baseline (610.862 us; speedup 1.0000x reference)
//
#include <hip/hip_runtime.h>
#include <hip/hip_fp16.h>

// ---------------------------------------------------------------------------
// MaskedGNN: 6-layer GCN, weight-free scaled-hidden formulation.
//  Store H' = dis * h  (fp16), FEATURE-SLICED layout: H[s][node][16] for
//  s=0..7 (slice = 3.2MB, fits one XCD L2). Aggregation grid: slice =
//  blockIdx&7 -> XCD steering makes all gathers L2-resident.
//  z_i = dis_i * ( sum_src H'_src + H'_i ); h' = dis * relu(z @ W + b).
//  CSR: LDS-radix partition by dst>>7; k_build also emits degree-sorted
//  processing order perm (kills degree divergence) + row_start/dis/x4.
//  GEMM: MFMA f32_16x16x32_f16, W split hi/lo fp16, fp32 accum, in-place,
//  sliced addressing. Last GEMM fuses the decoder matvec.
// ---------------------------------------------------------------------------

#define HW 128     // hidden width
#define NBMAX 1024 // max dst buckets (N <= 131072)
#define CAP 4096   // max edges per bucket staged in LDS

typedef _Float16 f16x8 __attribute__((ext_vector_type(8)));
typedef float f32x4 __attribute__((ext_vector_type(4)));

// ---------------- CSR build ----------------
__global__ void k_zero_i32(int* __restrict__ a, int n) {
    int i = blockIdx.x * 256 + threadIdx.x;
    if (i < n) a[i] = 0;
}

__global__ __launch_bounds__(256) void k_histb(const int* __restrict__ dstA,
                                               int* __restrict__ bcnt,
                                               int nb, int e, int nblk) {
    __shared__ int lh[NBMAX];
    for (int b = threadIdx.x; b < nb; b += 256) lh[b] = 0;
    __syncthreads();
    int blk = blockIdx.x;
    int c0 = (int)(((long long)e * blk) / nblk);
    int c1 = (int)(((long long)e * (blk + 1)) / nblk);
    for (int i = c0 + threadIdx.x; i < c1; i += 256) atomicAdd(&lh[dstA[i] >> 7], 1);
    __syncthreads();
    for (int b = threadIdx.x; b < nb; b += 256) {
        int v = lh[b];
        if (v) atomicAdd(&bcnt[b], v);
    }
}

__global__ void k_bscan(const int* __restrict__ bcnt, int* __restrict__ bstart,
                        int* __restrict__ bcur, int nb, int etot) {
    __shared__ int s[1024];
    int t = threadIdx.x;
    int d0 = (t < nb) ? bcnt[t] : 0;
    s[t] = d0;
    __syncthreads();
    for (int off = 1; off < 1024; off <<= 1) {
        int v = (t >= off) ? s[t - off] : 0;
        __syncthreads();
        s[t] += v;
        __syncthreads();
    }
    if (t < nb) {
        int ex = s[t] - d0;
        bstart[t] = ex;
        bcur[t] = ex;
    }
    if (t == 0) bstart[nb] = etot;
}

__global__ __launch_bounds__(256) void k_part(const int* __restrict__ srcA,
                                              const int* __restrict__ dstA,
                                              int* __restrict__ bcur,
                                              unsigned* __restrict__ stage,
                                              int nb, int e, int nblk) {
    __shared__ int lh[NBMAX];
    __shared__ int loff[NBMAX];
    for (int b = threadIdx.x; b < nb; b += 256) lh[b] = 0;
    __syncthreads();
    int blk = blockIdx.x;
    int c0 = (int)(((long long)e * blk) / nblk);
    int c1 = (int)(((long long)e * (blk + 1)) / nblk);
    for (int i = c0 + threadIdx.x; i < c1; i += 256) atomicAdd(&lh[dstA[i] >> 7], 1);
    __syncthreads();
    for (int b = threadIdx.x; b < nb; b += 256) {
        int v = lh[b];
        loff[b] = v ? atomicAdd(&bcur[b], v) : 0;
    }
    __syncthreads();
    for (int b = threadIdx.x; b < nb; b += 256) lh[b] = 0;
    __syncthreads();
    for (int i = c0 + threadIdx.x; i < c1; i += 256) {
        int d = dstA[i];
        int bk = d >> 7;
        int p = loff[bk] + atomicAdd(&lh[bk], 1);
        stage[p] = ((unsigned)srcA[i] << 7) | (unsigned)(d & 127);
    }
}

// one block per bucket: count+scan -> row_start/dis/x4, degree-sorted perm,
// LDS placement -> coalesced csr window write.
__global__ __launch_bounds__(256) void k_build(const unsigned* __restrict__ stage,
                                               const int* __restrict__ bstart,
                                               const float* __restrict__ x,
                                               int* __restrict__ row_start,
                                               float* __restrict__ dis,
                                               float4* __restrict__ x4,
                                               int* __restrict__ csr,
                                               int* __restrict__ perm,
                                               int n, int nb) {
    __shared__ int lcnt[128];
    __shared__ int sc[128];
    __shared__ int dbin[64];
    __shared__ int lcsr[CAP];
    int b = blockIdx.x, tid = threadIdx.x;
    int base = bstart[b], end = bstart[b + 1], cnt = end - base;
    int node0 = b << 7;

    if (tid < 128) lcnt[tid] = 0;
    if (tid < 64) dbin[tid] = 0;
    if (tid < 128) perm[(b << 7) + tid] = -1;
    __syncthreads();
    for (int j = tid; j < cnt; j += 256) atomicAdd(&lcnt[stage[base + j] & 127], 1);
    __syncthreads();
    int mydeg = (tid < 128) ? lcnt[tid] : 0;
    if (tid < 128) sc[tid] = mydeg;
    __syncthreads();
    for (int off = 1; off < 128; off <<= 1) {
        int v = (tid < 128 && tid >= off) ? sc[tid - off] : 0;
        __syncthreads();
        if (tid < 128) sc[tid] += v;
        __syncthreads();
    }
    int node = node0 + tid;
    bool valid = (tid < 128 && node < n);
    if (valid) {
        int excl = sc[tid] - mydeg;
        row_start[node] = base + excl;
        float dv = rsqrtf(1.f + (float)mydeg);
        dis[node] = dv;
        x4[node] = make_float4(x[node * 3] * dv, x[node * 3 + 1] * dv,
                               x[node * 3 + 2] * dv, 0.f);
        atomicAdd(&dbin[mydeg < 63 ? mydeg : 63], 1);
    }
    if (tid == 0 && b == nb - 1) row_start[n] = end;
    __syncthreads();
    if (tid == 0) {  // serial exclusive scan of 64 degree bins
        int s = 0;
#pragma unroll
        for (int i = 0; i < 64; ++i) { int c = dbin[i]; dbin[i] = s; s += c; }
    }
    __syncthreads();
    if (valid) {
        int r = atomicAdd(&dbin[mydeg < 63 ? mydeg : 63], 1);
        perm[(b << 7) + r] = node;
    }
    __syncthreads();
    if (tid < 128) sc[tid] = sc[tid] - mydeg;  // exclusive offsets
    if (tid < 128) lcnt[tid] = 0;
    __syncthreads();
    if (cnt <= CAP) {
        for (int j = tid; j < cnt; j += 256) {
            unsigned v = stage[base + j];
            int dl = v & 127;
            int p = atomicAdd(&lcnt[dl], 1);
            lcsr[sc[dl] + p] = (int)(v >> 7);
        }
        __syncthreads();
        for (int j = tid; j < cnt; j += 256) csr[base + j] = lcsr[j];
    } else {
        for (int j = tid; j < cnt; j += 256) {
            unsigned v = stage[base + j];
            int dl = v & 127;
            int p = atomicAdd(&lcnt[dl], 1);
            csr[base + sc[dl] + p] = (int)(v >> 7);
        }
    }
}

// ---------------- W prep: transpose + hi/lo fp16 split ----------------
__global__ void k_prep_wt(const float* __restrict__ Wp, __half* __restrict__ WTh,
                          __half* __restrict__ WTl, int total) {
    int t = blockIdx.x * 256 + threadIdx.x;
    if (t >= total) return;
    int l = t >> 14;
    int kc = t & 16383;
    int k = kc >> 7, c = kc & 127;
    float w = Wp[t];
    __half hi = __float2half_rn(w);
    __half lo = __float2half_rn(w - __half2float(hi));
    size_t o = ((size_t)l << 14) + (size_t)c * HW + k;
    WTh[o] = hi;
    WTl[o] = lo;
}

// ---------------- encoder ----------------
__global__ void k_enc_agg(const float4* __restrict__ x4, const int* __restrict__ rs,
                          const int* __restrict__ csr, const float* __restrict__ dis,
                          float4* __restrict__ zx, int n) {
    int i = blockIdx.x * 256 + threadIdx.x;
    if (i >= n) return;
    float4 a = x4[i];
    int e1 = rs[i + 1];
    for (int j = rs[i]; j < e1; ++j) {
        float4 v = x4[csr[j]];
        a.x += v.x; a.y += v.y; a.z += v.z;
    }
    float d = dis[i];
    zx[i] = make_float4(a.x * d, a.y * d, a.z * d, 0.f);
}

// writes H in sliced layout: H[(c>>4)*n + i][c&15]
__global__ void k_enc_gemm(const float4* __restrict__ zx, const float* __restrict__ We,
                           const float* __restrict__ be, const float* __restrict__ dis,
                           __half* __restrict__ H, int n) {
    int t = blockIdx.x * 256 + threadIdx.x;
    int i = t >> 7;
    int c = t & 127;
    if (i >= n) return;
    float4 z = zx[i];
    float v = z.x * We[c] + z.y * We[HW + c] + z.z * We[2 * HW + c] + be[c];
    H[((size_t)(c >> 4) * n + i) * 16 + (c & 15)] = __float2half_rn(fmaxf(v, 0.f) * dis[i]);
}

// ---------------- sliced aggregate: slice = blockIdx&7 (XCD-steered) --------
// 2 lanes per node (16 feats), 32 nodes/wave, degree-sorted perm order.
// 8 edges in flight per pair. Z[s][i] = fp16(dis_i*(H[s][i] + sum H[s][src])).
__global__ __launch_bounds__(256) void k_agg_sl(const __half* __restrict__ Hin,
                                                const int* __restrict__ rs,
                                                const int* __restrict__ csr,
                                                const int* __restrict__ perm,
                                                const float* __restrict__ dis,
                                                __half* __restrict__ Z, int n) {
    int s = blockIdx.x & 7;
    int chunk = blockIdx.x >> 3;
    int lane = threadIdx.x & 63, wave = threadIdx.x >> 6;
    int lg = lane & 1;
    int node = perm[(chunk << 7) + (wave << 5) + (lane >> 1)];  // -1 pad
    const __half* Hs = Hin + (size_t)s * n * 16;

    float a0[8], a1[8], a2[8], a3[8];
#pragma unroll
    for (int j = 0; j < 8; ++j) { a0[j] = 0.f; a1[j] = 0.f; a2[j] = 0.f; a3[j] = 0.f; }

    int e0 = 0, e1 = 0;
    if (node >= 0) {
        e0 = rs[node];
        e1 = rs[node + 1];
        f16x8 hv = *(const f16x8*)(Hs + (size_t)node * 16 + lg * 8);
#pragma unroll
        for (int j = 0; j < 8; ++j) a0[j] = (float)hv[j];
    }

    for (int base = e0; base < e1; base += 8) {
        int cnt = e1 - base;
        if (cnt > 8) cnt = 8;
        int sA0 = (base + 0 + lg < e1) ? csr[base + 0 + lg] : 0;
        int sA1 = (base + 2 + lg < e1) ? csr[base + 2 + lg] : 0;
        int sA2 = (base + 4 + lg < e1) ? csr[base + 4 + lg] : 0;
        int sA3 = (base + 6 + lg < e1) ? csr[base + 6 + lg] : 0;
        int m0 = __shfl(sA0, 0, 2), m1 = __shfl(sA0, 1, 2);
        int m2 = __shfl(sA1, 0, 2), m3 = __shfl(sA1, 1, 2);
        int m4 = __shfl(sA2, 0, 2), m5 = __shfl(sA2, 1, 2);
        int m6 = __shfl(sA3, 0, 2), m7 = __shfl(sA3, 1, 2);
        f16x8 z8 = (f16x8)(_Float16)0.f;
        f16x8 v0 = (0 < cnt) ? *(const f16x8*)(Hs + (size_t)m0 * 16 + lg * 8) : z8;
        f16x8 v1 = (1 < cnt) ? *(const f16x8*)(Hs + (size_t)m1 * 16 + lg * 8) : z8;
        f16x8 v2 = (2 < cnt) ? *(const f16x8*)(Hs + (size_t)m2 * 16 + lg * 8) : z8;
        f16x8 v3 = (3 < cnt) ? *(const f16x8*)(Hs + (size_t)m3 * 16 + lg * 8) : z8;
        f16x8 v4 = (4 < cnt) ? *(const f16x8*)(Hs + (size_t)m4 * 16 + lg * 8) : z8;
        f16x8 v5 = (5 < cnt) ? *(const f16x8*)(Hs + (size_t)m5 * 16 + lg * 8) : z8;
        f16x8 v6 = (6 < cnt) ? *(const f16x8*)(Hs + (size_t)m6 * 16 + lg * 8) : z8;
        f16x8 v7 = (7 < cnt) ? *(const f16x8*)(Hs + (size_t)m7 * 16 + lg * 8) : z8;
#pragma unroll
        for (int j = 0; j < 8; ++j) {
            a0[j] += (float)v0[j]; a1[j] += (float)v1[j];
            a2[j] += (float)v2[j]; a3[j] += (float)v3[j];
            a0[j] += (float)v4[j]; a1[j] += (float)v5[j];
            a2[j] += (float)v6[j]; a3[j] += (float)v7[j];
        }
    }

    if (node >= 0) {
        float d = dis[node];
        union { uint4 u; __half2 h[4]; } pk;
#pragma unroll
        for (int j = 0; j < 4; ++j) {
            float lo = d * ((a0[2 * j] + a1[2 * j]) + (a2[2 * j] + a3[2 * j]));
            float hi = d * ((a0[2 * j + 1] + a1[2 * j + 1]) + (a2[2 * j + 1] + a3[2 * j + 1]));
            pk.h[j] = __floats2half2_rn(lo, hi);
        }
        *(uint4*)(Z + ((size_t)s * n + node) * 16 + lg * 8) = pk.u;
    }
}

// ---------------- MFMA GEMM (sliced I/O): H' = dis*relu(Z@W+b), in place ----
// mode 0: write fp16 H' sliced. mode 1 (last layer): emit t[row] = H'.Wd.
// A slice for k-chunk ks, quarter q: s = 2ks + (q>>1), off = (q&1)*8.
#define GBM 256
__global__ __launch_bounds__(256) void k_gemm_mfma(const __half* __restrict__ Z,
                                                   const __half* __restrict__ WTh,
                                                   const __half* __restrict__ WTl,
                                                   const float* __restrict__ b,
                                                   const float* __restrict__ dis,
                                                   __half* __restrict__ Hout,
                                                   const float* __restrict__ Wd,
                                                   float* __restrict__ tout,
                                                   int mode, int n) {
    int wave = threadIdx.x >> 6, lane = threadIdx.x & 63;
    int q = lane >> 4, r16 = lane & 15;
    int row0 = blockIdx.x * GBM + wave * 64;

    f32x4 acc[4][8];
#pragma unroll
    for (int mt = 0; mt < 4; ++mt)
#pragma unroll
        for (int nt = 0; nt < 8; ++nt) acc[mt][nt] = (f32x4)0.f;

#pragma unroll
    for (int ks = 0; ks < 4; ++ks) {
        int asl = 2 * ks + (q >> 1);
        int aoff = (q & 1) * 8;
        f16x8 afr[4];
#pragma unroll
        for (int mt = 0; mt < 4; ++mt) {
            int row = row0 + mt * 16 + r16;
            row = row < n ? row : (n - 1);  // clamp; results discarded at store
            afr[mt] = *(const f16x8*)(Z + ((size_t)asl * n + row) * 16 + aoff);
        }
#pragma unroll
        for (int nt = 0; nt < 8; ++nt) {
            f16x8 bh = *(const f16x8*)(WTh + (size_t)(nt * 16 + r16) * HW + ks * 32 + q * 8);
            f16x8 bl = *(const f16x8*)(WTl + (size_t)(nt * 16 + r16) * HW + ks * 32 + q * 8);
#pragma unroll
            for (int mt = 0; mt < 4; ++mt) {
                acc[mt][nt] = __builtin_amdgcn_mfma_f32_16x16x32_f16(afr[mt], bh, acc[mt][nt], 0, 0, 0);
                acc[mt][nt] = __builtin_amdgcn_mfma_f32_16x16x32_f16(afr[mt], bl, acc[mt][nt], 0, 0, 0);
            }
        }
    }

    float dr[4][4];
#pragma unroll
    for (int mt = 0; mt < 4; ++mt)
#pragma unroll
        for (int r = 0; r < 4; ++r) {
            int row = row0 + mt * 16 + q * 4 + r;
            dr[mt][r] = (row < n) ? dis[row] : 0.f;
        }
    float bias[8];
#pragma unroll
    for (int nt = 0; nt < 8; ++nt) bias[nt] = b[nt * 16 + r16];

    if (mode == 0) {
#pragma unroll
        for (int nt = 0; nt < 8; ++nt) {
#pragma unroll
            for (int mt = 0; mt < 4; ++mt) {
#pragma unroll
                for (int r = 0; r < 4; ++r) {
                    int row = row0 + mt * 16 + q * 4 + r;
                    if (row < n) {
                        float v = fmaxf(acc[mt][nt][r] + bias[nt], 0.f) * dr[mt][r];
                        Hout[((size_t)nt * n + row) * 16 + r16] = __float2half_rn(v);
                    }
                }
            }
        }
    } else {
        float wd[8];
#pragma unroll
        for (int nt = 0; nt < 8; ++nt) wd[nt] = Wd[nt * 16 + r16];
#pragma unroll
        for (int mt = 0; mt < 4; ++mt) {
#pragma unroll
            for (int r = 0; r < 4; ++r) {
                float pr = 0.f;
#pragma unroll
                for (int nt = 0; nt < 8; ++nt)
                    pr += fmaxf(acc[mt][nt][r] + bias[nt], 0.f) * wd[nt];
                pr *= dr[mt][r];
#pragma unroll
                for (int off = 1; off < 16; off <<= 1) pr += __shfl_xor(pr, off, 16);
                if (r16 == 0) {
                    int row = row0 + mt * 16 + q * 4 + r;
                    if (row < n) tout[row] = pr;
                }
            }
        }
    }
}

// ---------------- decoder output ----------------
__global__ void k_dec_out(const float* __restrict__ t, const int* __restrict__ rs,
                          const int* __restrict__ csr, const float* __restrict__ dis,
                          const float* __restrict__ bdec, const float* __restrict__ mask,
                          float* __restrict__ out, int n) {
    int i = blockIdx.x * 256 + threadIdx.x;
    if (i >= n) return;
    float acc = t[i];
    int e1 = rs[i + 1];
    for (int j = rs[i]; j < e1; ++j) acc += t[csr[j]];
    out[i] = (dis[i] * acc + bdec[0]) * mask[i];
}

// ---------------------------------------------------------------------------
static inline size_t align256(size_t x) { return (x + 255) & ~(size_t)255; }

extern "C" void kernel_launch(void* const* d_in, const int* in_sizes, int n_in,
                              void* d_out, int out_size, void* d_ws, size_t ws_size,
                              hipStream_t stream) {
    const float* x     = (const float*)d_in[0];
    const float* mask  = (const float*)d_in[1];
    const int*   ei    = (const int*)d_in[2];
    const float* W_enc = (const float*)d_in[3];
    const float* b_enc = (const float*)d_in[4];
    const float* W_p   = (const float*)d_in[5];
    const float* b_p   = (const float*)d_in[6];
    const float* W_dec = (const float*)d_in[7];
    const float* b_dec = (const float*)d_in[8];

    const int N = in_sizes[1];
    const int E = in_sizes[2] / 2;
    const int* srcA = ei;
    const int* dstA = ei + E;
    const int NB = (N + 127) >> 7;  // dst buckets of 128 nodes (<= NBMAX)

    char* p = (char*)d_ws;
    size_t off = 0;
    auto carve = [&](size_t bytes) {
        void* r = p + off;
        off += align256(bytes);
        return r;
    };
    int*      bcnt      = (int*)carve((size_t)NB * 4);
    int*      bstart    = (int*)carve((size_t)(NB + 1) * 4);
    int*      bcur      = (int*)carve((size_t)NB * 4);
    int*      row_start = (int*)carve((size_t)(N + 1) * 4);
    int*      perm      = (int*)carve((size_t)NB * 128 * 4);
    unsigned* stage     = (unsigned*)carve((size_t)E * 4);
    int*      csr       = (int*)carve((size_t)E * 4);
    float*    dis       = (float*)carve((size_t)N * 4);
    float4*   x4        = (float4*)carve((size_t)N * 16);
    float4*   zx        = (float4*)carve((size_t)N * 16);
    float*    tdec      = (float*)carve((size_t)N * 4);
    __half*   WTh       = (__half*)carve((size_t)4 * HW * HW * 2);
    __half*   WTl       = (__half*)carve((size_t)4 * HW * HW * 2);
    __half*   HA        = (__half*)carve((size_t)N * HW * 2);
    __half*   HB        = (__half*)carve((size_t)N * HW * 2);

    const int gN   = (N + 255) / 256;
    const int gG   = (N + GBM - 1) / GBM;
    const int WPT  = 4 * HW * HW;
    const int PBLK = 256;

    // ---- CSR build (LDS-radix) + preps ----
    k_zero_i32<<<(NB + 255) / 256, 256, 0, stream>>>(bcnt, NB);
    k_histb<<<PBLK, 256, 0, stream>>>(dstA, bcnt, NB, E, PBLK);
    k_bscan<<<1, 1024, 0, stream>>>(bcnt, bstart, bcur, NB, E);
    k_part<<<PBLK, 256, 0, stream>>>(srcA, dstA, bcur, stage, NB, E, PBLK);
    k_build<<<NB, 256, 0, stream>>>(stage, bstart, x, row_start, dis, x4, csr, perm, N, NB);
    k_prep_wt<<<(WPT + 255) / 256, 256, 0, stream>>>(W_p, WTh, WTl, WPT);

    // ---- encoder ----
    k_enc_agg<<<gN, 256, 0, stream>>>(x4, row_start, csr, dis, zx, N);
    k_enc_gemm<<<(N * HW + 255) / 256, 256, 0, stream>>>(zx, W_enc, b_enc, dis, HA, N);

    // ---- 4 processor layers: sliced agg(Hin->Hoth), gemm in place on Hoth --
    __half* Hin = HA;
    __half* Hoth = HB;
    for (int l = 0; l < 4; ++l) {
        k_agg_sl<<<8 * NB, 256, 0, stream>>>(Hin, row_start, csr, perm, dis, Hoth, N);
        int mode = (l == 3) ? 1 : 0;
        k_gemm_mfma<<<gG, 256, 0, stream>>>(Hoth, WTh + (size_t)l * HW * HW,
                                            WTl + (size_t)l * HW * HW,
                                            b_p + (size_t)l * HW, dis, Hoth,
                                            W_dec, tdec, mode, N);
        __half* t = Hin; Hin = Hoth; Hoth = t;
    }

    // ---- decoder output ----
    k_dec_out<<<gN, 256, 0, stream>>>(tdec, row_start, csr, dis, b_dec, mask,
                                      (float*)d_out, N);
}

// Round 10
// 574.789 us; speedup vs baseline: 1.0628x; 1.0628x over previous
//
#include <hip/hip_runtime.h>
#include <hip/hip_fp16.h>

// ---------------------------------------------------------------------------
// MaskedGNN: 6-layer GCN, weight-free scaled-hidden formulation.
//  Store H' = dis * h  (fp16, row-major [N][128]). Per layer:
//    z_i = dis_i * ( sum_src H'_src + H'_i )   [pure gather-sum]
//    h_next' = dis * relu(z @ W + b)
//  CSR: LDS-radix partition by dst>>7. k_build emits row_start/dis/x4 and a
//  degree-sorted perm (within each 128-node bucket) used by the aggregator
//  so the 4 nodes of a wave have ~equal degree (no divergence inflation).
//  Aggregation: wave = 4 nodes x 16 lanes, 16B/lane (256B/row), 4-deep
//  unroll -> 16 rows (4KB) in flight per wave. GEMM: MFMA f32_16x16x32_f16,
//  W split hi/lo fp16 (W exact), fp32 accum, in-place; last GEMM fuses the
//  decoder matvec.
// ---------------------------------------------------------------------------

#define HW 128     // hidden width
#define NBMAX 1024 // max dst buckets (N <= 131072)
#define CAP 4096   // max edges per bucket staged in LDS

typedef _Float16 f16x8 __attribute__((ext_vector_type(8)));
typedef float f32x4 __attribute__((ext_vector_type(4)));

// ---------------- CSR build ----------------
__global__ void k_zero_i32(int* __restrict__ a, int n) {
    int i = blockIdx.x * 256 + threadIdx.x;
    if (i < n) a[i] = 0;
}

__global__ __launch_bounds__(256) void k_histb(const int* __restrict__ dstA,
                                               int* __restrict__ bcnt,
                                               int nb, int e, int nblk) {
    __shared__ int lh[NBMAX];
    for (int b = threadIdx.x; b < nb; b += 256) lh[b] = 0;
    __syncthreads();
    int blk = blockIdx.x;
    int c0 = (int)(((long long)e * blk) / nblk);
    int c1 = (int)(((long long)e * (blk + 1)) / nblk);
    for (int i = c0 + threadIdx.x; i < c1; i += 256) atomicAdd(&lh[dstA[i] >> 7], 1);
    __syncthreads();
    for (int b = threadIdx.x; b < nb; b += 256) {
        int v = lh[b];
        if (v) atomicAdd(&bcnt[b], v);
    }
}

__global__ void k_bscan(const int* __restrict__ bcnt, int* __restrict__ bstart,
                        int* __restrict__ bcur, int nb, int etot) {
    __shared__ int s[1024];
    int t = threadIdx.x;
    int d0 = (t < nb) ? bcnt[t] : 0;
    s[t] = d0;
    __syncthreads();
    for (int off = 1; off < 1024; off <<= 1) {
        int v = (t >= off) ? s[t - off] : 0;
        __syncthreads();
        s[t] += v;
        __syncthreads();
    }
    if (t < nb) {
        int ex = s[t] - d0;
        bstart[t] = ex;
        bcur[t] = ex;
    }
    if (t == 0) bstart[nb] = etot;
}

__global__ __launch_bounds__(256) void k_part(const int* __restrict__ srcA,
                                              const int* __restrict__ dstA,
                                              int* __restrict__ bcur,
                                              unsigned* __restrict__ stage,
                                              int nb, int e, int nblk) {
    __shared__ int lh[NBMAX];
    __shared__ int loff[NBMAX];
    for (int b = threadIdx.x; b < nb; b += 256) lh[b] = 0;
    __syncthreads();
    int blk = blockIdx.x;
    int c0 = (int)(((long long)e * blk) / nblk);
    int c1 = (int)(((long long)e * (blk + 1)) / nblk);
    for (int i = c0 + threadIdx.x; i < c1; i += 256) atomicAdd(&lh[dstA[i] >> 7], 1);
    __syncthreads();
    for (int b = threadIdx.x; b < nb; b += 256) {
        int v = lh[b];
        loff[b] = v ? atomicAdd(&bcur[b], v) : 0;
    }
    __syncthreads();
    for (int b = threadIdx.x; b < nb; b += 256) lh[b] = 0;
    __syncthreads();
    for (int i = c0 + threadIdx.x; i < c1; i += 256) {
        int d = dstA[i];
        int bk = d >> 7;
        int p = loff[bk] + atomicAdd(&lh[bk], 1);
        stage[p] = ((unsigned)srcA[i] << 7) | (unsigned)(d & 127);
    }
}

// one block per bucket: count+scan -> row_start/dis/x4, degree-sorted perm,
// LDS placement -> coalesced csr window write.
__global__ __launch_bounds__(256) void k_build(const unsigned* __restrict__ stage,
                                               const int* __restrict__ bstart,
                                               const float* __restrict__ x,
                                               int* __restrict__ row_start,
                                               float* __restrict__ dis,
                                               float4* __restrict__ x4,
                                               int* __restrict__ csr,
                                               int* __restrict__ perm,
                                               int n, int nb) {
    __shared__ int lcnt[128];
    __shared__ int sc[128];
    __shared__ int dbin[64];
    __shared__ int lcsr[CAP];
    int b = blockIdx.x, tid = threadIdx.x;
    int base = bstart[b], end = bstart[b + 1], cnt = end - base;
    int node0 = b << 7;

    if (tid < 128) lcnt[tid] = 0;
    if (tid < 64) dbin[tid] = 0;
    if (tid < 128) perm[(b << 7) + tid] = -1;
    __syncthreads();
    for (int j = tid; j < cnt; j += 256) atomicAdd(&lcnt[stage[base + j] & 127], 1);
    __syncthreads();
    int mydeg = (tid < 128) ? lcnt[tid] : 0;
    if (tid < 128) sc[tid] = mydeg;
    __syncthreads();
    for (int off = 1; off < 128; off <<= 1) {
        int v = (tid < 128 && tid >= off) ? sc[tid - off] : 0;
        __syncthreads();
        if (tid < 128) sc[tid] += v;
        __syncthreads();
    }
    int node = node0 + tid;
    bool valid = (tid < 128 && node < n);
    if (valid) {
        int excl = sc[tid] - mydeg;
        row_start[node] = base + excl;
        float dv = rsqrtf(1.f + (float)mydeg);
        dis[node] = dv;
        x4[node] = make_float4(x[node * 3] * dv, x[node * 3 + 1] * dv,
                               x[node * 3 + 2] * dv, 0.f);
        atomicAdd(&dbin[mydeg < 63 ? mydeg : 63], 1);
    }
    if (tid == 0 && b == nb - 1) row_start[n] = end;
    __syncthreads();
    if (tid == 0) {  // serial exclusive scan of 64 degree bins
        int s = 0;
#pragma unroll
        for (int i = 0; i < 64; ++i) { int c = dbin[i]; dbin[i] = s; s += c; }
    }
    __syncthreads();
    if (valid) {
        int r = atomicAdd(&dbin[mydeg < 63 ? mydeg : 63], 1);
        perm[(b << 7) + r] = node;
    }
    __syncthreads();
    if (tid < 128) sc[tid] = sc[tid] - mydeg;  // exclusive offsets
    if (tid < 128) lcnt[tid] = 0;
    __syncthreads();
    if (cnt <= CAP) {
        for (int j = tid; j < cnt; j += 256) {
            unsigned v = stage[base + j];
            int dl = v & 127;
            int p = atomicAdd(&lcnt[dl], 1);
            lcsr[sc[dl] + p] = (int)(v >> 7);
        }
        __syncthreads();
        for (int j = tid; j < cnt; j += 256) csr[base + j] = lcsr[j];
    } else {
        for (int j = tid; j < cnt; j += 256) {
            unsigned v = stage[base + j];
            int dl = v & 127;
            int p = atomicAdd(&lcnt[dl], 1);
            csr[base + sc[dl] + p] = (int)(v >> 7);
        }
    }
}

// ---------------- W prep: transpose + hi/lo fp16 split ----------------
__global__ void k_prep_wt(const float* __restrict__ Wp, __half* __restrict__ WTh,
                          __half* __restrict__ WTl, int total) {
    int t = blockIdx.x * 256 + threadIdx.x;
    if (t >= total) return;
    int l = t >> 14;
    int kc = t & 16383;
    int k = kc >> 7, c = kc & 127;
    float w = Wp[t];
    __half hi = __float2half_rn(w);
    __half lo = __float2half_rn(w - __half2float(hi));
    size_t o = ((size_t)l << 14) + (size_t)c * HW + k;
    WTh[o] = hi;
    WTl[o] = lo;
}

// ---------------- encoder ----------------
__global__ void k_enc_agg(const float4* __restrict__ x4, const int* __restrict__ rs,
                          const int* __restrict__ csr, const float* __restrict__ dis,
                          float4* __restrict__ zx, int n) {
    int i = blockIdx.x * 256 + threadIdx.x;
    if (i >= n) return;
    float4 a = x4[i];
    int e1 = rs[i + 1];
    for (int j = rs[i]; j < e1; ++j) {
        float4 v = x4[csr[j]];
        a.x += v.x; a.y += v.y; a.z += v.z;
    }
    float d = dis[i];
    zx[i] = make_float4(a.x * d, a.y * d, a.z * d, 0.f);
}

__global__ void k_enc_gemm(const float4* __restrict__ zx, const float* __restrict__ We,
                           const float* __restrict__ be, const float* __restrict__ dis,
                           __half* __restrict__ H, int n) {
    int t = blockIdx.x * 256 + threadIdx.x;
    int i = t >> 7;
    int c = t & 127;
    if (i >= n) return;
    float4 z = zx[i];
    float v = z.x * We[c] + z.y * We[HW + c] + z.z * We[2 * HW + c] + be[c];
    H[(size_t)i * HW + c] = __float2half_rn(fmaxf(v, 0.f) * dis[i]);
}

// ---------------- width-128 aggregate: 4 perm-sorted nodes/wave -------------
// 16 lanes/node, 16B/lane (256B/row), 4-deep unroll (16 rows in flight/wave).
// perm gives the wave 4 nodes of ~equal degree -> no divergence inflation.
// Z[i] = fp16( dis_i * ( H'[i] + sum_src H'[src] ) )
__global__ __launch_bounds__(256) void k_agg128(const __half* __restrict__ Hin,
                                                const int* __restrict__ rs,
                                                const int* __restrict__ csr,
                                                const int* __restrict__ perm,
                                                const float* __restrict__ dis,
                                                __half* __restrict__ Z, int n) {
    int wave = threadIdx.x >> 6, lane = threadIdx.x & 63;
    int lg = lane & 15;  // lane in 16-lane group
    int idx = (blockIdx.x * 4 + wave) * 4 + (lane >> 4);
    int node = perm[idx];  // -1 pad
    bool active = node >= 0;

    float a0[8], a1[8], a2[8], a3[8];
#pragma unroll
    for (int j = 0; j < 8; ++j) { a0[j] = 0.f; a1[j] = 0.f; a2[j] = 0.f; a3[j] = 0.f; }

    int e0 = 0, e1 = 0;
    if (active) {
        e0 = rs[node];
        e1 = rs[node + 1];
        f16x8 hv = *(const f16x8*)(Hin + (size_t)node * HW + lg * 8);
#pragma unroll
        for (int j = 0; j < 8; ++j) a0[j] = (float)hv[j];
    }

    for (int base = e0; base < e1; base += 16) {
        int cnt = e1 - base;
        if (cnt > 16) cnt = 16;
        int sl = (base + lg < e1) ? csr[base + lg] : 0;
        int k = 0;
        for (; k + 4 <= cnt; k += 4) {
            int s0 = __shfl(sl, k + 0, 16);
            int s1 = __shfl(sl, k + 1, 16);
            int s2 = __shfl(sl, k + 2, 16);
            int s3 = __shfl(sl, k + 3, 16);
            f16x8 v0 = *(const f16x8*)(Hin + (size_t)s0 * HW + lg * 8);
            f16x8 v1 = *(const f16x8*)(Hin + (size_t)s1 * HW + lg * 8);
            f16x8 v2 = *(const f16x8*)(Hin + (size_t)s2 * HW + lg * 8);
            f16x8 v3 = *(const f16x8*)(Hin + (size_t)s3 * HW + lg * 8);
#pragma unroll
            for (int j = 0; j < 8; ++j) {
                a0[j] += (float)v0[j];
                a1[j] += (float)v1[j];
                a2[j] += (float)v2[j];
                a3[j] += (float)v3[j];
            }
        }
        for (; k < cnt; ++k) {
            int s = __shfl(sl, k, 16);
            f16x8 v = *(const f16x8*)(Hin + (size_t)s * HW + lg * 8);
#pragma unroll
            for (int j = 0; j < 8; ++j) a0[j] += (float)v[j];
        }
    }

    if (active) {
        float d = dis[node];
        union { uint4 u; __half2 h[4]; } pk;
#pragma unroll
        for (int j = 0; j < 4; ++j) {
            float lo = d * ((a0[2 * j] + a1[2 * j]) + (a2[2 * j] + a3[2 * j]));
            float hi = d * ((a0[2 * j + 1] + a1[2 * j + 1]) + (a2[2 * j + 1] + a3[2 * j + 1]));
            pk.h[j] = __floats2half2_rn(lo, hi);
        }
        *(uint4*)(Z + (size_t)node * HW + lg * 8) = pk.u;
    }
}

// ---------------- MFMA GEMM: H' = dis * relu(Z @ W + b), in place -----------
// mode 0: write fp16 H'. mode 1 (last layer): skip H, emit t[row] = H'.Wd.
// Layout (16x16x32): A row=lane&15, k=(lane>>4)*8+j ; B col=lane&15, same k;
// C/D col=lane&15, row=(lane>>4)*4+reg.
#define GBM 256
__global__ __launch_bounds__(256) void k_gemm_mfma(const __half* __restrict__ Z,
                                                   const __half* __restrict__ WTh,
                                                   const __half* __restrict__ WTl,
                                                   const float* __restrict__ b,
                                                   const float* __restrict__ dis,
                                                   __half* __restrict__ Hout,
                                                   const float* __restrict__ Wd,
                                                   float* __restrict__ tout,
                                                   int mode, int n) {
    int wave = threadIdx.x >> 6, lane = threadIdx.x & 63;
    int q = lane >> 4, r16 = lane & 15;
    int row0 = blockIdx.x * GBM + wave * 64;

    f32x4 acc[4][8];
#pragma unroll
    for (int mt = 0; mt < 4; ++mt)
#pragma unroll
        for (int nt = 0; nt < 8; ++nt) acc[mt][nt] = (f32x4)0.f;

#pragma unroll
    for (int ks = 0; ks < 4; ++ks) {
        f16x8 afr[4];
#pragma unroll
        for (int mt = 0; mt < 4; ++mt) {
            int row = row0 + mt * 16 + r16;
            row = row < n ? row : (n - 1);  // clamp; results discarded at store
            afr[mt] = *(const f16x8*)(Z + (size_t)row * HW + ks * 32 + q * 8);
        }
#pragma unroll
        for (int nt = 0; nt < 8; ++nt) {
            f16x8 bh = *(const f16x8*)(WTh + (size_t)(nt * 16 + r16) * HW + ks * 32 + q * 8);
            f16x8 bl = *(const f16x8*)(WTl + (size_t)(nt * 16 + r16) * HW + ks * 32 + q * 8);
#pragma unroll
            for (int mt = 0; mt < 4; ++mt) {
                acc[mt][nt] = __builtin_amdgcn_mfma_f32_16x16x32_f16(afr[mt], bh, acc[mt][nt], 0, 0, 0);
                acc[mt][nt] = __builtin_amdgcn_mfma_f32_16x16x32_f16(afr[mt], bl, acc[mt][nt], 0, 0, 0);
            }
        }
    }

    float dr[4][4];
#pragma unroll
    for (int mt = 0; mt < 4; ++mt)
#pragma unroll
        for (int r = 0; r < 4; ++r) {
            int row = row0 + mt * 16 + q * 4 + r;
            dr[mt][r] = (row < n) ? dis[row] : 0.f;
        }
    float bias[8];
#pragma unroll
    for (int nt = 0; nt < 8; ++nt) bias[nt] = b[nt * 16 + r16];

    if (mode == 0) {
#pragma unroll
        for (int nt = 0; nt < 8; ++nt) {
#pragma unroll
            for (int mt = 0; mt < 4; ++mt) {
#pragma unroll
                for (int r = 0; r < 4; ++r) {
                    int row = row0 + mt * 16 + q * 4 + r;
                    if (row < n) {
                        float v = fmaxf(acc[mt][nt][r] + bias[nt], 0.f) * dr[mt][r];
                        Hout[(size_t)row * HW + nt * 16 + r16] = __float2half_rn(v);
                    }
                }
            }
        }
    } else {
        float wd[8];
#pragma unroll
        for (int nt = 0; nt < 8; ++nt) wd[nt] = Wd[nt * 16 + r16];
#pragma unroll
        for (int mt = 0; mt < 4; ++mt) {
#pragma unroll
            for (int r = 0; r < 4; ++r) {
                float pr = 0.f;
#pragma unroll
                for (int nt = 0; nt < 8; ++nt)
                    pr += fmaxf(acc[mt][nt][r] + bias[nt], 0.f) * wd[nt];
                pr *= dr[mt][r];
#pragma unroll
                for (int off = 1; off < 16; off <<= 1) pr += __shfl_xor(pr, off, 16);
                if (r16 == 0) {
                    int row = row0 + mt * 16 + q * 4 + r;
                    if (row < n) tout[row] = pr;
                }
            }
        }
    }
}

// ---------------- decoder output ----------------
__global__ void k_dec_out(const float* __restrict__ t, const int* __restrict__ rs,
                          const int* __restrict__ csr, const float* __restrict__ dis,
                          const float* __restrict__ bdec, const float* __restrict__ mask,
                          float* __restrict__ out, int n) {
    int i = blockIdx.x * 256 + threadIdx.x;
    if (i >= n) return;
    float acc = t[i];
    int e1 = rs[i + 1];
    for (int j = rs[i]; j < e1; ++j) acc += t[csr[j]];
    out[i] = (dis[i] * acc + bdec[0]) * mask[i];
}

// ---------------------------------------------------------------------------
static inline size_t align256(size_t x) { return (x + 255) & ~(size_t)255; }

extern "C" void kernel_launch(void* const* d_in, const int* in_sizes, int n_in,
                              void* d_out, int out_size, void* d_ws, size_t ws_size,
                              hipStream_t stream) {
    const float* x     = (const float*)d_in[0];
    const float* mask  = (const float*)d_in[1];
    const int*   ei    = (const int*)d_in[2];
    const float* W_enc = (const float*)d_in[3];
    const float* b_enc = (const float*)d_in[4];
    const float* W_p   = (const float*)d_in[5];
    const float* b_p   = (const float*)d_in[6];
    const float* W_dec = (const float*)d_in[7];
    const float* b_dec = (const float*)d_in[8];

    const int N = in_sizes[1];
    const int E = in_sizes[2] / 2;
    const int* srcA = ei;
    const int* dstA = ei + E;
    const int NB = (N + 127) >> 7;  // dst buckets of 128 nodes (<= NBMAX)

    char* p = (char*)d_ws;
    size_t off = 0;
    auto carve = [&](size_t bytes) {
        void* r = p + off;
        off += align256(bytes);
        return r;
    };
    int*      bcnt      = (int*)carve((size_t)NB * 4);
    int*      bstart    = (int*)carve((size_t)(NB + 1) * 4);
    int*      bcur      = (int*)carve((size_t)NB * 4);
    int*      row_start = (int*)carve((size_t)(N + 1) * 4);
    int*      perm      = (int*)carve((size_t)NB * 128 * 4);
    unsigned* stage     = (unsigned*)carve((size_t)E * 4);
    int*      csr       = (int*)carve((size_t)E * 4);
    float*    dis       = (float*)carve((size_t)N * 4);
    float4*   x4        = (float4*)carve((size_t)N * 16);
    float4*   zx        = (float4*)carve((size_t)N * 16);
    float*    tdec      = (float*)carve((size_t)N * 4);
    __half*   WTh       = (__half*)carve((size_t)4 * HW * HW * 2);
    __half*   WTl       = (__half*)carve((size_t)4 * HW * HW * 2);
    __half*   HA        = (__half*)carve((size_t)N * HW * 2);
    __half*   HB        = (__half*)carve((size_t)N * HW * 2);

    const int gN   = (N + 255) / 256;
    const int gAgg = (NB * 128) / 16;  // 16 perm slots per block
    const int gG   = (N + GBM - 1) / GBM;
    const int WPT  = 4 * HW * HW;
    const int PBLK = 256;

    // ---- CSR build (LDS-radix) + preps ----
    k_zero_i32<<<(NB + 255) / 256, 256, 0, stream>>>(bcnt, NB);
    k_histb<<<PBLK, 256, 0, stream>>>(dstA, bcnt, NB, E, PBLK);
    k_bscan<<<1, 1024, 0, stream>>>(bcnt, bstart, bcur, NB, E);
    k_part<<<PBLK, 256, 0, stream>>>(srcA, dstA, bcur, stage, NB, E, PBLK);
    k_build<<<NB, 256, 0, stream>>>(stage, bstart, x, row_start, dis, x4, csr, perm, N, NB);
    k_prep_wt<<<(WPT + 255) / 256, 256, 0, stream>>>(W_p, WTh, WTl, WPT);

    // ---- encoder ----
    k_enc_agg<<<gN, 256, 0, stream>>>(x4, row_start, csr, dis, zx, N);
    k_enc_gemm<<<(N * HW + 255) / 256, 256, 0, stream>>>(zx, W_enc, b_enc, dis, HA, N);

    // ---- 4 processor layers: agg(Hin->Hoth), gemm in place on Hoth ----
    __half* Hin = HA;
    __half* Hoth = HB;
    for (int l = 0; l < 4; ++l) {
        k_agg128<<<gAgg, 256, 0, stream>>>(Hin, row_start, csr, perm, dis, Hoth, N);
        int mode = (l == 3) ? 1 : 0;
        k_gemm_mfma<<<gG, 256, 0, stream>>>(Hoth, WTh + (size_t)l * HW * HW,
                                            WTl + (size_t)l * HW * HW,
                                            b_p + (size_t)l * HW, dis, Hoth,
                                            W_dec, tdec, mode, N);
        __half* t = Hin; Hin = Hoth; Hoth = t;
    }

    // ---- decoder output ----
    k_dec_out<<<gN, 256, 0, stream>>>(tdec, row_start, csr, dis, b_dec, mask,
                                      (float*)d_out, N);
}

// Round 11
// 531.707 us; speedup vs baseline: 1.1489x; 1.0810x over previous
//
#include <hip/hip_runtime.h>
#include <hip/hip_fp16.h>

// ---------------------------------------------------------------------------
// MaskedGNN: 6-layer GCN, weight-free scaled-hidden formulation.
//  Store H' = dis * h  (fp16, row-major [N][128]). Per layer:
//    z_i = dis_i * ( sum_src H'_src + H'_i )   [pure gather-sum]
//    h_next' = dis * relu(z @ W + b)
//  CSR: LDS-radix partition by dst>>7. histb saves per-(block,bucket) counts
//  so part needs no re-histogram and no global reservation atomics.
//  Aggregation (R8 structure, consecutive nodes): wave = 4 nodes x 16 lanes,
//  16B/lane (256B/row), 8-deep unroll -> 32 rows (8KB) in flight per wave.
//  GEMM: MFMA f32_16x16x32_f16, W split hi/lo fp16 (W exact), fp32 accum,
//  in-place; last GEMM fuses the decoder matvec.
// ---------------------------------------------------------------------------

#define HW 128     // hidden width
#define NBMAX 1024 // max dst buckets (N <= 131072)
#define CAP 4096   // max edges per bucket staged in LDS
#define PBLK 256   // partition blocks (== threads in k_soff2)

typedef _Float16 f16x8 __attribute__((ext_vector_type(8)));
typedef float f32x4 __attribute__((ext_vector_type(4)));

// ---------------- CSR build ----------------
__global__ void k_zero_i32(int* __restrict__ a, int n) {
    int i = blockIdx.x * 256 + threadIdx.x;
    if (i < n) a[i] = 0;
}

// per-block LDS bucket histogram; saves per-block counts + global bucket sums
__global__ __launch_bounds__(256) void k_histb(const int* __restrict__ dstA,
                                               int* __restrict__ bcnt,
                                               int* __restrict__ pcnt,
                                               int nb, int e, int nblk) {
    __shared__ int lh[NBMAX];
    for (int b = threadIdx.x; b < nb; b += 256) lh[b] = 0;
    __syncthreads();
    int blk = blockIdx.x;
    int c0 = (int)(((long long)e * blk) / nblk);
    int c1 = (int)(((long long)e * (blk + 1)) / nblk);
    for (int i = c0 + threadIdx.x; i < c1; i += 256) atomicAdd(&lh[dstA[i] >> 7], 1);
    __syncthreads();
    for (int b = threadIdx.x; b < nb; b += 256) {
        int v = lh[b];
        pcnt[(size_t)blk * nb + b] = v;
        if (v) atomicAdd(&bcnt[b], v);
    }
}

__global__ void k_bscan(const int* __restrict__ bcnt, int* __restrict__ bstart,
                        int nb, int etot) {
    __shared__ int s[1024];
    int t = threadIdx.x;
    int d0 = (t < nb) ? bcnt[t] : 0;
    s[t] = d0;
    __syncthreads();
    for (int off = 1; off < 1024; off <<= 1) {
        int v = (t >= off) ? s[t - off] : 0;
        __syncthreads();
        s[t] += v;
        __syncthreads();
    }
    if (t < nb) bstart[t] = s[t] - d0;
    if (t == 0) bstart[nb] = etot;
}

// per-bucket scan of the PBLK per-block counts -> exact staging offsets
__global__ __launch_bounds__(PBLK) void k_soff2(const int* __restrict__ pcnt,
                                                const int* __restrict__ bstart,
                                                int* __restrict__ soff, int nb) {
    __shared__ int s[PBLK];
    int b = blockIdx.x, t = threadIdx.x;
    int v = pcnt[(size_t)t * nb + b];
    s[t] = v;
    __syncthreads();
    for (int off = 1; off < PBLK; off <<= 1) {
        int u = (t >= off) ? s[t - off] : 0;
        __syncthreads();
        s[t] += u;
        __syncthreads();
    }
    soff[(size_t)t * nb + b] = bstart[b] + s[t] - v;
}

// partition edges into bucket windows using precomputed offsets (no re-hist,
// no global atomics). stage = (src<<7)|(dst&127).
__global__ __launch_bounds__(256) void k_part(const int* __restrict__ srcA,
                                              const int* __restrict__ dstA,
                                              const int* __restrict__ soff,
                                              unsigned* __restrict__ stage,
                                              int nb, int e, int nblk) {
    __shared__ int loff[NBMAX];
    __shared__ int lh[NBMAX];
    int blk = blockIdx.x;
    for (int b = threadIdx.x; b < nb; b += 256) {
        loff[b] = soff[(size_t)blk * nb + b];
        lh[b] = 0;
    }
    __syncthreads();
    int c0 = (int)(((long long)e * blk) / nblk);
    int c1 = (int)(((long long)e * (blk + 1)) / nblk);
    for (int i = c0 + threadIdx.x; i < c1; i += 256) {
        int d = dstA[i];
        int bk = d >> 7;
        int p = loff[bk] + atomicAdd(&lh[bk], 1);
        stage[p] = ((unsigned)srcA[i] << 7) | (unsigned)(d & 127);
    }
}

// one block per bucket: count+scan -> row_start/dis/x4, LDS placement ->
// coalesced csr window write.
__global__ __launch_bounds__(256) void k_build(const unsigned* __restrict__ stage,
                                               const int* __restrict__ bstart,
                                               const float* __restrict__ x,
                                               int* __restrict__ row_start,
                                               float* __restrict__ dis,
                                               float4* __restrict__ x4,
                                               int* __restrict__ csr, int n, int nb) {
    __shared__ int lcnt[128];
    __shared__ int sc[128];
    __shared__ int lcsr[CAP];
    int b = blockIdx.x, tid = threadIdx.x;
    int base = bstart[b], end = bstart[b + 1], cnt = end - base;
    int node0 = b << 7;

    if (tid < 128) lcnt[tid] = 0;
    __syncthreads();
    for (int j = tid; j < cnt; j += 256) atomicAdd(&lcnt[stage[base + j] & 127], 1);
    __syncthreads();
    if (tid < 128) sc[tid] = lcnt[tid];
    __syncthreads();
    for (int off = 1; off < 128; off <<= 1) {
        int v = (tid < 128 && tid >= off) ? sc[tid - off] : 0;
        __syncthreads();
        if (tid < 128) sc[tid] += v;
        __syncthreads();
    }
    int node = node0 + tid;
    if (tid < 128 && node < n) {
        int excl = sc[tid] - lcnt[tid];
        row_start[node] = base + excl;
        float dv = rsqrtf(1.f + (float)lcnt[tid]);
        dis[node] = dv;
        x4[node] = make_float4(x[node * 3] * dv, x[node * 3 + 1] * dv,
                               x[node * 3 + 2] * dv, 0.f);
    }
    if (tid == 0 && b == nb - 1) row_start[n] = end;
    __syncthreads();
    if (tid < 128) sc[tid] = sc[tid] - lcnt[tid];  // exclusive offsets
    if (tid < 128) lcnt[tid] = 0;
    __syncthreads();
    if (cnt <= CAP) {
        for (int j = tid; j < cnt; j += 256) {
            unsigned v = stage[base + j];
            int dl = v & 127;
            int p = atomicAdd(&lcnt[dl], 1);
            lcsr[sc[dl] + p] = (int)(v >> 7);
        }
        __syncthreads();
        for (int j = tid; j < cnt; j += 256) csr[base + j] = lcsr[j];
    } else {
        for (int j = tid; j < cnt; j += 256) {
            unsigned v = stage[base + j];
            int dl = v & 127;
            int p = atomicAdd(&lcnt[dl], 1);
            csr[base + sc[dl] + p] = (int)(v >> 7);
        }
    }
}

// ---------------- W prep: transpose + hi/lo fp16 split ----------------
__global__ void k_prep_wt(const float* __restrict__ Wp, __half* __restrict__ WTh,
                          __half* __restrict__ WTl, int total) {
    int t = blockIdx.x * 256 + threadIdx.x;
    if (t >= total) return;
    int l = t >> 14;
    int kc = t & 16383;
    int k = kc >> 7, c = kc & 127;
    float w = Wp[t];
    __half hi = __float2half_rn(w);
    __half lo = __float2half_rn(w - __half2float(hi));
    size_t o = ((size_t)l << 14) + (size_t)c * HW + k;
    WTh[o] = hi;
    WTl[o] = lo;
}

// ---------------- encoder ----------------
__global__ void k_enc_agg(const float4* __restrict__ x4, const int* __restrict__ rs,
                          const int* __restrict__ csr, const float* __restrict__ dis,
                          float4* __restrict__ zx, int n) {
    int i = blockIdx.x * 256 + threadIdx.x;
    if (i >= n) return;
    float4 a = x4[i];
    int e1 = rs[i + 1];
    for (int j = rs[i]; j < e1; ++j) {
        float4 v = x4[csr[j]];
        a.x += v.x; a.y += v.y; a.z += v.z;
    }
    float d = dis[i];
    zx[i] = make_float4(a.x * d, a.y * d, a.z * d, 0.f);
}

__global__ void k_enc_gemm(const float4* __restrict__ zx, const float* __restrict__ We,
                           const float* __restrict__ be, const float* __restrict__ dis,
                           __half* __restrict__ H, int n) {
    int t = blockIdx.x * 256 + threadIdx.x;
    int i = t >> 7;
    int c = t & 127;
    if (i >= n) return;
    float4 z = zx[i];
    float v = z.x * We[c] + z.y * We[HW + c] + z.z * We[2 * HW + c] + be[c];
    H[(size_t)i * HW + c] = __float2half_rn(fmaxf(v, 0.f) * dis[i]);
}

// ---------------- width-128 aggregate: 4 consecutive nodes/wave -------------
// 16 lanes/node, 16B/lane (256B/row), 8-deep unroll (32 rows in flight/wave).
// Z[i] = fp16( dis_i * ( H'[i] + sum_src H'[src] ) )
__global__ __launch_bounds__(256) void k_agg128(const __half* __restrict__ Hin,
                                                const int* __restrict__ rs,
                                                const int* __restrict__ csr,
                                                const float* __restrict__ dis,
                                                __half* __restrict__ Z, int n) {
    int wave = threadIdx.x >> 6, lane = threadIdx.x & 63;
    int lg = lane & 15;  // lane in 16-lane group
    int node = (blockIdx.x * 4 + wave) * 4 + (lane >> 4);
    bool active = node < n;

    float a0[8], a1[8], a2[8], a3[8];
#pragma unroll
    for (int j = 0; j < 8; ++j) { a0[j] = 0.f; a1[j] = 0.f; a2[j] = 0.f; a3[j] = 0.f; }

    int e0 = 0, e1 = 0;
    if (active) {
        e0 = rs[node];
        e1 = rs[node + 1];
        f16x8 hv = *(const f16x8*)(Hin + (size_t)node * HW + lg * 8);
#pragma unroll
        for (int j = 0; j < 8; ++j) a0[j] = (float)hv[j];
    }

    for (int base = e0; base < e1; base += 16) {
        int cnt = e1 - base;
        if (cnt > 16) cnt = 16;
        int sl = (base + lg < e1) ? csr[base + lg] : 0;
        int k = 0;
        for (; k + 8 <= cnt; k += 8) {
            int s0 = __shfl(sl, k + 0, 16);
            int s1 = __shfl(sl, k + 1, 16);
            int s2 = __shfl(sl, k + 2, 16);
            int s3 = __shfl(sl, k + 3, 16);
            int s4 = __shfl(sl, k + 4, 16);
            int s5 = __shfl(sl, k + 5, 16);
            int s6 = __shfl(sl, k + 6, 16);
            int s7 = __shfl(sl, k + 7, 16);
            f16x8 v0 = *(const f16x8*)(Hin + (size_t)s0 * HW + lg * 8);
            f16x8 v1 = *(const f16x8*)(Hin + (size_t)s1 * HW + lg * 8);
            f16x8 v2 = *(const f16x8*)(Hin + (size_t)s2 * HW + lg * 8);
            f16x8 v3 = *(const f16x8*)(Hin + (size_t)s3 * HW + lg * 8);
            f16x8 v4 = *(const f16x8*)(Hin + (size_t)s4 * HW + lg * 8);
            f16x8 v5 = *(const f16x8*)(Hin + (size_t)s5 * HW + lg * 8);
            f16x8 v6 = *(const f16x8*)(Hin + (size_t)s6 * HW + lg * 8);
            f16x8 v7 = *(const f16x8*)(Hin + (size_t)s7 * HW + lg * 8);
#pragma unroll
            for (int j = 0; j < 8; ++j) {
                a0[j] += (float)v0[j];
                a1[j] += (float)v1[j];
                a2[j] += (float)v2[j];
                a3[j] += (float)v3[j];
                a0[j] += (float)v4[j];
                a1[j] += (float)v5[j];
                a2[j] += (float)v6[j];
                a3[j] += (float)v7[j];
            }
        }
        for (; k + 4 <= cnt; k += 4) {
            int s0 = __shfl(sl, k + 0, 16);
            int s1 = __shfl(sl, k + 1, 16);
            int s2 = __shfl(sl, k + 2, 16);
            int s3 = __shfl(sl, k + 3, 16);
            f16x8 v0 = *(const f16x8*)(Hin + (size_t)s0 * HW + lg * 8);
            f16x8 v1 = *(const f16x8*)(Hin + (size_t)s1 * HW + lg * 8);
            f16x8 v2 = *(const f16x8*)(Hin + (size_t)s2 * HW + lg * 8);
            f16x8 v3 = *(const f16x8*)(Hin + (size_t)s3 * HW + lg * 8);
#pragma unroll
            for (int j = 0; j < 8; ++j) {
                a0[j] += (float)v0[j];
                a1[j] += (float)v1[j];
                a2[j] += (float)v2[j];
                a3[j] += (float)v3[j];
            }
        }
        for (; k < cnt; ++k) {
            int s = __shfl(sl, k, 16);
            f16x8 v = *(const f16x8*)(Hin + (size_t)s * HW + lg * 8);
#pragma unroll
            for (int j = 0; j < 8; ++j) a0[j] += (float)v[j];
        }
    }

    if (active) {
        float d = dis[node];
        union { uint4 u; __half2 h[4]; } pk;
#pragma unroll
        for (int j = 0; j < 4; ++j) {
            float lo = d * ((a0[2 * j] + a1[2 * j]) + (a2[2 * j] + a3[2 * j]));
            float hi = d * ((a0[2 * j + 1] + a1[2 * j + 1]) + (a2[2 * j + 1] + a3[2 * j + 1]));
            pk.h[j] = __floats2half2_rn(lo, hi);
        }
        *(uint4*)(Z + (size_t)node * HW + lg * 8) = pk.u;
    }
}

// ---------------- MFMA GEMM: H' = dis * relu(Z @ W + b), in place -----------
// mode 0: write fp16 H'. mode 1 (last layer): skip H, emit t[row] = H'.Wd.
// Layout (16x16x32): A row=lane&15, k=(lane>>4)*8+j ; B col=lane&15, same k;
// C/D col=lane&15, row=(lane>>4)*4+reg.
#define GBM 256
__global__ __launch_bounds__(256) void k_gemm_mfma(const __half* __restrict__ Z,
                                                   const __half* __restrict__ WTh,
                                                   const __half* __restrict__ WTl,
                                                   const float* __restrict__ b,
                                                   const float* __restrict__ dis,
                                                   __half* __restrict__ Hout,
                                                   const float* __restrict__ Wd,
                                                   float* __restrict__ tout,
                                                   int mode, int n) {
    int wave = threadIdx.x >> 6, lane = threadIdx.x & 63;
    int q = lane >> 4, r16 = lane & 15;
    int row0 = blockIdx.x * GBM + wave * 64;

    f32x4 acc[4][8];
#pragma unroll
    for (int mt = 0; mt < 4; ++mt)
#pragma unroll
        for (int nt = 0; nt < 8; ++nt) acc[mt][nt] = (f32x4)0.f;

#pragma unroll
    for (int ks = 0; ks < 4; ++ks) {
        f16x8 afr[4];
#pragma unroll
        for (int mt = 0; mt < 4; ++mt) {
            int row = row0 + mt * 16 + r16;
            row = row < n ? row : (n - 1);  // clamp; results discarded at store
            afr[mt] = *(const f16x8*)(Z + (size_t)row * HW + ks * 32 + q * 8);
        }
#pragma unroll
        for (int nt = 0; nt < 8; ++nt) {
            f16x8 bh = *(const f16x8*)(WTh + (size_t)(nt * 16 + r16) * HW + ks * 32 + q * 8);
            f16x8 bl = *(const f16x8*)(WTl + (size_t)(nt * 16 + r16) * HW + ks * 32 + q * 8);
#pragma unroll
            for (int mt = 0; mt < 4; ++mt) {
                acc[mt][nt] = __builtin_amdgcn_mfma_f32_16x16x32_f16(afr[mt], bh, acc[mt][nt], 0, 0, 0);
                acc[mt][nt] = __builtin_amdgcn_mfma_f32_16x16x32_f16(afr[mt], bl, acc[mt][nt], 0, 0, 0);
            }
        }
    }

    float dr[4][4];
#pragma unroll
    for (int mt = 0; mt < 4; ++mt)
#pragma unroll
        for (int r = 0; r < 4; ++r) {
            int row = row0 + mt * 16 + q * 4 + r;
            dr[mt][r] = (row < n) ? dis[row] : 0.f;
        }
    float bias[8];
#pragma unroll
    for (int nt = 0; nt < 8; ++nt) bias[nt] = b[nt * 16 + r16];

    if (mode == 0) {
#pragma unroll
        for (int nt = 0; nt < 8; ++nt) {
#pragma unroll
            for (int mt = 0; mt < 4; ++mt) {
#pragma unroll
                for (int r = 0; r < 4; ++r) {
                    int row = row0 + mt * 16 + q * 4 + r;
                    if (row < n) {
                        float v = fmaxf(acc[mt][nt][r] + bias[nt], 0.f) * dr[mt][r];
                        Hout[(size_t)row * HW + nt * 16 + r16] = __float2half_rn(v);
                    }
                }
            }
        }
    } else {
        float wd[8];
#pragma unroll
        for (int nt = 0; nt < 8; ++nt) wd[nt] = Wd[nt * 16 + r16];
#pragma unroll
        for (int mt = 0; mt < 4; ++mt) {
#pragma unroll
            for (int r = 0; r < 4; ++r) {
                float pr = 0.f;
#pragma unroll
                for (int nt = 0; nt < 8; ++nt)
                    pr += fmaxf(acc[mt][nt][r] + bias[nt], 0.f) * wd[nt];
                pr *= dr[mt][r];
#pragma unroll
                for (int off = 1; off < 16; off <<= 1) pr += __shfl_xor(pr, off, 16);
                if (r16 == 0) {
                    int row = row0 + mt * 16 + q * 4 + r;
                    if (row < n) tout[row] = pr;
                }
            }
        }
    }
}

// ---------------- decoder output ----------------
__global__ void k_dec_out(const float* __restrict__ t, const int* __restrict__ rs,
                          const int* __restrict__ csr, const float* __restrict__ dis,
                          const float* __restrict__ bdec, const float* __restrict__ mask,
                          float* __restrict__ out, int n) {
    int i = blockIdx.x * 256 + threadIdx.x;
    if (i >= n) return;
    float acc = t[i];
    int e1 = rs[i + 1];
    for (int j = rs[i]; j < e1; ++j) acc += t[csr[j]];
    out[i] = (dis[i] * acc + bdec[0]) * mask[i];
}

// ---------------------------------------------------------------------------
static inline size_t align256(size_t x) { return (x + 255) & ~(size_t)255; }

extern "C" void kernel_launch(void* const* d_in, const int* in_sizes, int n_in,
                              void* d_out, int out_size, void* d_ws, size_t ws_size,
                              hipStream_t stream) {
    const float* x     = (const float*)d_in[0];
    const float* mask  = (const float*)d_in[1];
    const int*   ei    = (const int*)d_in[2];
    const float* W_enc = (const float*)d_in[3];
    const float* b_enc = (const float*)d_in[4];
    const float* W_p   = (const float*)d_in[5];
    const float* b_p   = (const float*)d_in[6];
    const float* W_dec = (const float*)d_in[7];
    const float* b_dec = (const float*)d_in[8];

    const int N = in_sizes[1];
    const int E = in_sizes[2] / 2;
    const int* srcA = ei;
    const int* dstA = ei + E;
    const int NB = (N + 127) >> 7;  // dst buckets of 128 nodes (<= NBMAX)

    char* p = (char*)d_ws;
    size_t off = 0;
    auto carve = [&](size_t bytes) {
        void* r = p + off;
        off += align256(bytes);
        return r;
    };
    int*      bcnt      = (int*)carve((size_t)NB * 4);
    int*      bstart    = (int*)carve((size_t)(NB + 1) * 4);
    int*      pcnt      = (int*)carve((size_t)PBLK * NB * 4);
    int*      soff      = (int*)carve((size_t)PBLK * NB * 4);
    int*      row_start = (int*)carve((size_t)(N + 1) * 4);
    unsigned* stage     = (unsigned*)carve((size_t)E * 4);
    int*      csr       = (int*)carve((size_t)E * 4);
    float*    dis       = (float*)carve((size_t)N * 4);
    float4*   x4        = (float4*)carve((size_t)N * 16);
    float4*   zx        = (float4*)carve((size_t)N * 16);
    float*    tdec      = (float*)carve((size_t)N * 4);
    __half*   WTh       = (__half*)carve((size_t)4 * HW * HW * 2);
    __half*   WTl       = (__half*)carve((size_t)4 * HW * HW * 2);
    __half*   HA        = (__half*)carve((size_t)N * HW * 2);
    __half*   HB        = (__half*)carve((size_t)N * HW * 2);

    const int gN   = (N + 255) / 256;
    const int gAgg = (N + 15) / 16;
    const int gG   = (N + GBM - 1) / GBM;
    const int WPT  = 4 * HW * HW;

    // ---- CSR build (LDS-radix, no re-hist) + preps ----
    k_zero_i32<<<(NB + 255) / 256, 256, 0, stream>>>(bcnt, NB);
    k_histb<<<PBLK, 256, 0, stream>>>(dstA, bcnt, pcnt, NB, E, PBLK);
    k_bscan<<<1, 1024, 0, stream>>>(bcnt, bstart, NB, E);
    k_soff2<<<NB, PBLK, 0, stream>>>(pcnt, bstart, soff, NB);
    k_part<<<PBLK, 256, 0, stream>>>(srcA, dstA, soff, stage, NB, E, PBLK);
    k_build<<<NB, 256, 0, stream>>>(stage, bstart, x, row_start, dis, x4, csr, N, NB);
    k_prep_wt<<<(WPT + 255) / 256, 256, 0, stream>>>(W_p, WTh, WTl, WPT);

    // ---- encoder ----
    k_enc_agg<<<gN, 256, 0, stream>>>(x4, row_start, csr, dis, zx, N);
    k_enc_gemm<<<(N * HW + 255) / 256, 256, 0, stream>>>(zx, W_enc, b_enc, dis, HA, N);

    // ---- 4 processor layers: agg(Hin->Hoth), gemm in place on Hoth ----
    __half* Hin = HA;
    __half* Hoth = HB;
    for (int l = 0; l < 4; ++l) {
        k_agg128<<<gAgg, 256, 0, stream>>>(Hin, row_start, csr, dis, Hoth, N);
        int mode = (l == 3) ? 1 : 0;
        k_gemm_mfma<<<gG, 256, 0, stream>>>(Hoth, WTh + (size_t)l * HW * HW,
                                            WTl + (size_t)l * HW * HW,
                                            b_p + (size_t)l * HW, dis, Hoth,
                                            W_dec, tdec, mode, N);
        __half* t = Hin; Hin = Hoth; Hoth = t;
    }

    // ---- decoder output ----
    k_dec_out<<<gN, 256, 0, stream>>>(tdec, row_start, csr, dis, b_dec, mask,
                                      (float*)d_out, N);
}

// Round 12
// 513.212 us; speedup vs baseline: 1.1903x; 1.0360x over previous
//
#include <hip/hip_runtime.h>
#include <hip/hip_fp16.h>

// ---------------------------------------------------------------------------
// MaskedGNN: 6-layer GCN, weight-free scaled-hidden formulation.
//  Store H' = dis * h  (fp16, row-major [N][128]). Per layer:
//    z_i = dis_i * ( sum_src H'_src + H'_i )   [pure gather-sum]
//    h_next' = dis * relu(z @ W + b)
//  CSR: LDS-radix partition by dst>>7; histb saves per-(block,bucket) counts
//  so part needs no re-histogram and no global reservation atomics.
//  Aggregation (R8-proven): wave = 4 consecutive nodes x 16 lanes, 16B/lane
//  (256B/row), 4-deep unroll -> 16 rows (4KB) in flight per wave. This sits
//  at the structural L2-capacity floor (each XCD pulls ~all of H once:
//  FETCH ~188MB ~ 8 x 22MB) at the ~3.1 TB/s L2-miss service rate.
//  GEMM: MFMA f32_16x16x32_f16, W split hi/lo fp16 (W exact), fp32 accum,
//  in-place; last GEMM fuses the decoder matvec.
// ---------------------------------------------------------------------------

#define HW 128     // hidden width
#define NBMAX 1024 // max dst buckets (N <= 131072)
#define CAP 4096   // max edges per bucket staged in LDS
#define PBLK 256   // partition blocks (== threads in k_soff2)

typedef _Float16 f16x8 __attribute__((ext_vector_type(8)));
typedef float f32x4 __attribute__((ext_vector_type(4)));

// ---------------- CSR build ----------------
__global__ void k_zero_i32(int* __restrict__ a, int n) {
    int i = blockIdx.x * 256 + threadIdx.x;
    if (i < n) a[i] = 0;
}

// per-block LDS bucket histogram; saves per-block counts + global bucket sums
__global__ __launch_bounds__(256) void k_histb(const int* __restrict__ dstA,
                                               int* __restrict__ bcnt,
                                               int* __restrict__ pcnt,
                                               int nb, int e, int nblk) {
    __shared__ int lh[NBMAX];
    for (int b = threadIdx.x; b < nb; b += 256) lh[b] = 0;
    __syncthreads();
    int blk = blockIdx.x;
    int c0 = (int)(((long long)e * blk) / nblk);
    int c1 = (int)(((long long)e * (blk + 1)) / nblk);
    for (int i = c0 + threadIdx.x; i < c1; i += 256) atomicAdd(&lh[dstA[i] >> 7], 1);
    __syncthreads();
    for (int b = threadIdx.x; b < nb; b += 256) {
        int v = lh[b];
        pcnt[(size_t)blk * nb + b] = v;
        if (v) atomicAdd(&bcnt[b], v);
    }
}

__global__ void k_bscan(const int* __restrict__ bcnt, int* __restrict__ bstart,
                        int nb, int etot) {
    __shared__ int s[1024];
    int t = threadIdx.x;
    int d0 = (t < nb) ? bcnt[t] : 0;
    s[t] = d0;
    __syncthreads();
    for (int off = 1; off < 1024; off <<= 1) {
        int v = (t >= off) ? s[t - off] : 0;
        __syncthreads();
        s[t] += v;
        __syncthreads();
    }
    if (t < nb) bstart[t] = s[t] - d0;
    if (t == 0) bstart[nb] = etot;
}

// per-bucket scan of the PBLK per-block counts -> exact staging offsets
__global__ __launch_bounds__(PBLK) void k_soff2(const int* __restrict__ pcnt,
                                                const int* __restrict__ bstart,
                                                int* __restrict__ soff, int nb) {
    __shared__ int s[PBLK];
    int b = blockIdx.x, t = threadIdx.x;
    int v = pcnt[(size_t)t * nb + b];
    s[t] = v;
    __syncthreads();
    for (int off = 1; off < PBLK; off <<= 1) {
        int u = (t >= off) ? s[t - off] : 0;
        __syncthreads();
        s[t] += u;
        __syncthreads();
    }
    soff[(size_t)t * nb + b] = bstart[b] + s[t] - v;
}

// partition edges into bucket windows using precomputed offsets (no re-hist,
// no global atomics). stage = (src<<7)|(dst&127).
__global__ __launch_bounds__(256) void k_part(const int* __restrict__ srcA,
                                              const int* __restrict__ dstA,
                                              const int* __restrict__ soff,
                                              unsigned* __restrict__ stage,
                                              int nb, int e, int nblk) {
    __shared__ int loff[NBMAX];
    __shared__ int lh[NBMAX];
    int blk = blockIdx.x;
    for (int b = threadIdx.x; b < nb; b += 256) {
        loff[b] = soff[(size_t)blk * nb + b];
        lh[b] = 0;
    }
    __syncthreads();
    int c0 = (int)(((long long)e * blk) / nblk);
    int c1 = (int)(((long long)e * (blk + 1)) / nblk);
    for (int i = c0 + threadIdx.x; i < c1; i += 256) {
        int d = dstA[i];
        int bk = d >> 7;
        int p = loff[bk] + atomicAdd(&lh[bk], 1);
        stage[p] = ((unsigned)srcA[i] << 7) | (unsigned)(d & 127);
    }
}

// one block per bucket: count+scan -> row_start/dis/x4, LDS placement ->
// coalesced csr window write.
__global__ __launch_bounds__(256) void k_build(const unsigned* __restrict__ stage,
                                               const int* __restrict__ bstart,
                                               const float* __restrict__ x,
                                               int* __restrict__ row_start,
                                               float* __restrict__ dis,
                                               float4* __restrict__ x4,
                                               int* __restrict__ csr, int n, int nb) {
    __shared__ int lcnt[128];
    __shared__ int sc[128];
    __shared__ int lcsr[CAP];
    int b = blockIdx.x, tid = threadIdx.x;
    int base = bstart[b], end = bstart[b + 1], cnt = end - base;
    int node0 = b << 7;

    if (tid < 128) lcnt[tid] = 0;
    __syncthreads();
    for (int j = tid; j < cnt; j += 256) atomicAdd(&lcnt[stage[base + j] & 127], 1);
    __syncthreads();
    if (tid < 128) sc[tid] = lcnt[tid];
    __syncthreads();
    for (int off = 1; off < 128; off <<= 1) {
        int v = (tid < 128 && tid >= off) ? sc[tid - off] : 0;
        __syncthreads();
        if (tid < 128) sc[tid] += v;
        __syncthreads();
    }
    int node = node0 + tid;
    if (tid < 128 && node < n) {
        int excl = sc[tid] - lcnt[tid];
        row_start[node] = base + excl;
        float dv = rsqrtf(1.f + (float)lcnt[tid]);
        dis[node] = dv;
        x4[node] = make_float4(x[node * 3] * dv, x[node * 3 + 1] * dv,
                               x[node * 3 + 2] * dv, 0.f);
    }
    if (tid == 0 && b == nb - 1) row_start[n] = end;
    __syncthreads();
    if (tid < 128) sc[tid] = sc[tid] - lcnt[tid];  // exclusive offsets
    if (tid < 128) lcnt[tid] = 0;
    __syncthreads();
    if (cnt <= CAP) {
        for (int j = tid; j < cnt; j += 256) {
            unsigned v = stage[base + j];
            int dl = v & 127;
            int p = atomicAdd(&lcnt[dl], 1);
            lcsr[sc[dl] + p] = (int)(v >> 7);
        }
        __syncthreads();
        for (int j = tid; j < cnt; j += 256) csr[base + j] = lcsr[j];
    } else {
        for (int j = tid; j < cnt; j += 256) {
            unsigned v = stage[base + j];
            int dl = v & 127;
            int p = atomicAdd(&lcnt[dl], 1);
            csr[base + sc[dl] + p] = (int)(v >> 7);
        }
    }
}

// ---------------- W prep: transpose + hi/lo fp16 split ----------------
__global__ void k_prep_wt(const float* __restrict__ Wp, __half* __restrict__ WTh,
                          __half* __restrict__ WTl, int total) {
    int t = blockIdx.x * 256 + threadIdx.x;
    if (t >= total) return;
    int l = t >> 14;
    int kc = t & 16383;
    int k = kc >> 7, c = kc & 127;
    float w = Wp[t];
    __half hi = __float2half_rn(w);
    __half lo = __float2half_rn(w - __half2float(hi));
    size_t o = ((size_t)l << 14) + (size_t)c * HW + k;
    WTh[o] = hi;
    WTl[o] = lo;
}

// ---------------- encoder ----------------
__global__ void k_enc_agg(const float4* __restrict__ x4, const int* __restrict__ rs,
                          const int* __restrict__ csr, const float* __restrict__ dis,
                          float4* __restrict__ zx, int n) {
    int i = blockIdx.x * 256 + threadIdx.x;
    if (i >= n) return;
    float4 a = x4[i];
    int e1 = rs[i + 1];
    for (int j = rs[i]; j < e1; ++j) {
        float4 v = x4[csr[j]];
        a.x += v.x; a.y += v.y; a.z += v.z;
    }
    float d = dis[i];
    zx[i] = make_float4(a.x * d, a.y * d, a.z * d, 0.f);
}

__global__ void k_enc_gemm(const float4* __restrict__ zx, const float* __restrict__ We,
                           const float* __restrict__ be, const float* __restrict__ dis,
                           __half* __restrict__ H, int n) {
    int t = blockIdx.x * 256 + threadIdx.x;
    int i = t >> 7;
    int c = t & 127;
    if (i >= n) return;
    float4 z = zx[i];
    float v = z.x * We[c] + z.y * We[HW + c] + z.z * We[2 * HW + c] + be[c];
    H[(size_t)i * HW + c] = __float2half_rn(fmaxf(v, 0.f) * dis[i]);
}

// ---------------- width-128 aggregate: 4 consecutive nodes/wave (R8) --------
// 16 lanes/node, 16B/lane (256B/row), 4-deep unroll (16 rows in flight/wave).
// Z[i] = fp16( dis_i * ( H'[i] + sum_src H'[src] ) )
__global__ __launch_bounds__(256) void k_agg128(const __half* __restrict__ Hin,
                                                const int* __restrict__ rs,
                                                const int* __restrict__ csr,
                                                const float* __restrict__ dis,
                                                __half* __restrict__ Z, int n) {
    int wave = threadIdx.x >> 6, lane = threadIdx.x & 63;
    int lg = lane & 15;  // lane in 16-lane group
    int node = (blockIdx.x * 4 + wave) * 4 + (lane >> 4);
    bool active = node < n;

    float a0[8], a1[8], a2[8], a3[8];
#pragma unroll
    for (int j = 0; j < 8; ++j) { a0[j] = 0.f; a1[j] = 0.f; a2[j] = 0.f; a3[j] = 0.f; }

    int e0 = 0, e1 = 0;
    if (active) {
        e0 = rs[node];
        e1 = rs[node + 1];
        f16x8 hv = *(const f16x8*)(Hin + (size_t)node * HW + lg * 8);
#pragma unroll
        for (int j = 0; j < 8; ++j) a0[j] = (float)hv[j];
    }

    for (int base = e0; base < e1; base += 16) {
        int cnt = e1 - base;
        if (cnt > 16) cnt = 16;
        int sl = (base + lg < e1) ? csr[base + lg] : 0;
        int k = 0;
        for (; k + 4 <= cnt; k += 4) {
            int s0 = __shfl(sl, k + 0, 16);
            int s1 = __shfl(sl, k + 1, 16);
            int s2 = __shfl(sl, k + 2, 16);
            int s3 = __shfl(sl, k + 3, 16);
            f16x8 v0 = *(const f16x8*)(Hin + (size_t)s0 * HW + lg * 8);
            f16x8 v1 = *(const f16x8*)(Hin + (size_t)s1 * HW + lg * 8);
            f16x8 v2 = *(const f16x8*)(Hin + (size_t)s2 * HW + lg * 8);
            f16x8 v3 = *(const f16x8*)(Hin + (size_t)s3 * HW + lg * 8);
#pragma unroll
            for (int j = 0; j < 8; ++j) {
                a0[j] += (float)v0[j];
                a1[j] += (float)v1[j];
                a2[j] += (float)v2[j];
                a3[j] += (float)v3[j];
            }
        }
        for (; k < cnt; ++k) {
            int s = __shfl(sl, k, 16);
            f16x8 v = *(const f16x8*)(Hin + (size_t)s * HW + lg * 8);
#pragma unroll
            for (int j = 0; j < 8; ++j) a0[j] += (float)v[j];
        }
    }

    if (active) {
        float d = dis[node];
        union { uint4 u; __half2 h[4]; } pk;
#pragma unroll
        for (int j = 0; j < 4; ++j) {
            float lo = d * ((a0[2 * j] + a1[2 * j]) + (a2[2 * j] + a3[2 * j]));
            float hi = d * ((a0[2 * j + 1] + a1[2 * j + 1]) + (a2[2 * j + 1] + a3[2 * j + 1]));
            pk.h[j] = __floats2half2_rn(lo, hi);
        }
        *(uint4*)(Z + (size_t)node * HW + lg * 8) = pk.u;
    }
}

// ---------------- MFMA GEMM: H' = dis * relu(Z @ W + b), in place -----------
// mode 0: write fp16 H'. mode 1 (last layer): skip H, emit t[row] = H'.Wd.
// Layout (16x16x32): A row=lane&15, k=(lane>>4)*8+j ; B col=lane&15, same k;
// C/D col=lane&15, row=(lane>>4)*4+reg.
#define GBM 256
__global__ __launch_bounds__(256) void k_gemm_mfma(const __half* __restrict__ Z,
                                                   const __half* __restrict__ WTh,
                                                   const __half* __restrict__ WTl,
                                                   const float* __restrict__ b,
                                                   const float* __restrict__ dis,
                                                   __half* __restrict__ Hout,
                                                   const float* __restrict__ Wd,
                                                   float* __restrict__ tout,
                                                   int mode, int n) {
    int wave = threadIdx.x >> 6, lane = threadIdx.x & 63;
    int q = lane >> 4, r16 = lane & 15;
    int row0 = blockIdx.x * GBM + wave * 64;

    f32x4 acc[4][8];
#pragma unroll
    for (int mt = 0; mt < 4; ++mt)
#pragma unroll
        for (int nt = 0; nt < 8; ++nt) acc[mt][nt] = (f32x4)0.f;

#pragma unroll
    for (int ks = 0; ks < 4; ++ks) {
        f16x8 afr[4];
#pragma unroll
        for (int mt = 0; mt < 4; ++mt) {
            int row = row0 + mt * 16 + r16;
            row = row < n ? row : (n - 1);  // clamp; results discarded at store
            afr[mt] = *(const f16x8*)(Z + (size_t)row * HW + ks * 32 + q * 8);
        }
#pragma unroll
        for (int nt = 0; nt < 8; ++nt) {
            f16x8 bh = *(const f16x8*)(WTh + (size_t)(nt * 16 + r16) * HW + ks * 32 + q * 8);
            f16x8 bl = *(const f16x8*)(WTl + (size_t)(nt * 16 + r16) * HW + ks * 32 + q * 8);
#pragma unroll
            for (int mt = 0; mt < 4; ++mt) {
                acc[mt][nt] = __builtin_amdgcn_mfma_f32_16x16x32_f16(afr[mt], bh, acc[mt][nt], 0, 0, 0);
                acc[mt][nt] = __builtin_amdgcn_mfma_f32_16x16x32_f16(afr[mt], bl, acc[mt][nt], 0, 0, 0);
            }
        }
    }

    float dr[4][4];
#pragma unroll
    for (int mt = 0; mt < 4; ++mt)
#pragma unroll
        for (int r = 0; r < 4; ++r) {
            int row = row0 + mt * 16 + q * 4 + r;
            dr[mt][r] = (row < n) ? dis[row] : 0.f;
        }
    float bias[8];
#pragma unroll
    for (int nt = 0; nt < 8; ++nt) bias[nt] = b[nt * 16 + r16];

    if (mode == 0) {
#pragma unroll
        for (int nt = 0; nt < 8; ++nt) {
#pragma unroll
            for (int mt = 0; mt < 4; ++mt) {
#pragma unroll
                for (int r = 0; r < 4; ++r) {
                    int row = row0 + mt * 16 + q * 4 + r;
                    if (row < n) {
                        float v = fmaxf(acc[mt][nt][r] + bias[nt], 0.f) * dr[mt][r];
                        Hout[(size_t)row * HW + nt * 16 + r16] = __float2half_rn(v);
                    }
                }
            }
        }
    } else {
        float wd[8];
#pragma unroll
        for (int nt = 0; nt < 8; ++nt) wd[nt] = Wd[nt * 16 + r16];
#pragma unroll
        for (int mt = 0; mt < 4; ++mt) {
#pragma unroll
            for (int r = 0; r < 4; ++r) {
                float pr = 0.f;
#pragma unroll
                for (int nt = 0; nt < 8; ++nt)
                    pr += fmaxf(acc[mt][nt][r] + bias[nt], 0.f) * wd[nt];
                pr *= dr[mt][r];
#pragma unroll
                for (int off = 1; off < 16; off <<= 1) pr += __shfl_xor(pr, off, 16);
                if (r16 == 0) {
                    int row = row0 + mt * 16 + q * 4 + r;
                    if (row < n) tout[row] = pr;
                }
            }
        }
    }
}

// ---------------- decoder output ----------------
__global__ void k_dec_out(const float* __restrict__ t, const int* __restrict__ rs,
                          const int* __restrict__ csr, const float* __restrict__ dis,
                          const float* __restrict__ bdec, const float* __restrict__ mask,
                          float* __restrict__ out, int n) {
    int i = blockIdx.x * 256 + threadIdx.x;
    if (i >= n) return;
    float acc = t[i];
    int e1 = rs[i + 1];
    for (int j = rs[i]; j < e1; ++j) acc += t[csr[j]];
    out[i] = (dis[i] * acc + bdec[0]) * mask[i];
}

// ---------------------------------------------------------------------------
static inline size_t align256(size_t x) { return (x + 255) & ~(size_t)255; }

extern "C" void kernel_launch(void* const* d_in, const int* in_sizes, int n_in,
                              void* d_out, int out_size, void* d_ws, size_t ws_size,
                              hipStream_t stream) {
    const float* x     = (const float*)d_in[0];
    const float* mask  = (const float*)d_in[1];
    const int*   ei    = (const int*)d_in[2];
    const float* W_enc = (const float*)d_in[3];
    const float* b_enc = (const float*)d_in[4];
    const float* W_p   = (const float*)d_in[5];
    const float* b_p   = (const float*)d_in[6];
    const float* W_dec = (const float*)d_in[7];
    const float* b_dec = (const float*)d_in[8];

    const int N = in_sizes[1];
    const int E = in_sizes[2] / 2;
    const int* srcA = ei;
    const int* dstA = ei + E;
    const int NB = (N + 127) >> 7;  // dst buckets of 128 nodes (<= NBMAX)

    char* p = (char*)d_ws;
    size_t off = 0;
    auto carve = [&](size_t bytes) {
        void* r = p + off;
        off += align256(bytes);
        return r;
    };
    int*      bcnt      = (int*)carve((size_t)NB * 4);
    int*      bstart    = (int*)carve((size_t)(NB + 1) * 4);
    int*      pcnt      = (int*)carve((size_t)PBLK * NB * 4);
    int*      soff      = (int*)carve((size_t)PBLK * NB * 4);
    int*      row_start = (int*)carve((size_t)(N + 1) * 4);
    unsigned* stage     = (unsigned*)carve((size_t)E * 4);
    int*      csr       = (int*)carve((size_t)E * 4);
    float*    dis       = (float*)carve((size_t)N * 4);
    float4*   x4        = (float4*)carve((size_t)N * 16);
    float4*   zx        = (float4*)carve((size_t)N * 16);
    float*    tdec      = (float*)carve((size_t)N * 4);
    __half*   WTh       = (__half*)carve((size_t)4 * HW * HW * 2);
    __half*   WTl       = (__half*)carve((size_t)4 * HW * HW * 2);
    __half*   HA        = (__half*)carve((size_t)N * HW * 2);
    __half*   HB        = (__half*)carve((size_t)N * HW * 2);

    const int gN   = (N + 255) / 256;
    const int gAgg = (N + 15) / 16;
    const int gG   = (N + GBM - 1) / GBM;
    const int WPT  = 4 * HW * HW;

    // ---- CSR build (LDS-radix, no re-hist) + preps ----
    k_zero_i32<<<(NB + 255) / 256, 256, 0, stream>>>(bcnt, NB);
    k_histb<<<PBLK, 256, 0, stream>>>(dstA, bcnt, pcnt, NB, E, PBLK);
    k_bscan<<<1, 1024, 0, stream>>>(bcnt, bstart, NB, E);
    k_soff2<<<NB, PBLK, 0, stream>>>(pcnt, bstart, soff, NB);
    k_part<<<PBLK, 256, 0, stream>>>(srcA, dstA, soff, stage, NB, E, PBLK);
    k_build<<<NB, 256, 0, stream>>>(stage, bstart, x, row_start, dis, x4, csr, N, NB);
    k_prep_wt<<<(WPT + 255) / 256, 256, 0, stream>>>(W_p, WTh, WTl, WPT);

    // ---- encoder ----
    k_enc_agg<<<gN, 256, 0, stream>>>(x4, row_start, csr, dis, zx, N);
    k_enc_gemm<<<(N * HW + 255) / 256, 256, 0, stream>>>(zx, W_enc, b_enc, dis, HA, N);

    // ---- 4 processor layers: agg(Hin->Hoth), gemm in place on Hoth ----
    __half* Hin = HA;
    __half* Hoth = HB;
    for (int l = 0; l < 4; ++l) {
        k_agg128<<<gAgg, 256, 0, stream>>>(Hin, row_start, csr, dis, Hoth, N);
        int mode = (l == 3) ? 1 : 0;
        k_gemm_mfma<<<gG, 256, 0, stream>>>(Hoth, WTh + (size_t)l * HW * HW,
                                            WTl + (size_t)l * HW * HW,
                                            b_p + (size_t)l * HW, dis, Hoth,
                                            W_dec, tdec, mode, N);
        __half* t = Hin; Hin = Hoth; Hoth = t;
    }

    // ---- decoder output ----
    k_dec_out<<<gN, 256, 0, stream>>>(tdec, row_start, csr, dis, b_dec, mask,
                                      (float*)d_out, N);
}

// Round 13
// 506.795 us; speedup vs baseline: 1.2053x; 1.0127x over previous
//
#include <hip/hip_runtime.h>
#include <hip/hip_fp16.h>

// ---------------------------------------------------------------------------
// MaskedGNN: 6-layer GCN, weight-free scaled-hidden formulation.
//  Store H' = dis * h  (fp16, row-major [N][128]). Per layer (FUSED kernel):
//    Phase A: z_i = dis_i * ( sum_src H'_src + H'_i )  -> fp16 LDS tile
//    Phase B: h_next' = dis * relu(z @ W + b) via MFMA from LDS (no Z buffer)
//  CSR: LDS-radix partition by dst>>7 (R12-proven build chain).
//  Aggregation structure (R8-proven): wave = 4 consecutive nodes x 16 lanes,
//  16B/lane, 4-deep unroll. Block = 4 waves = 16 nodes = one MFMA row-tile.
//  GEMM: MFMA f32_16x16x32_f16, W split hi/lo fp16 (W exact), fp32 accum.
//  Last layer's Phase B emits the decoder matvec t instead of H.
// ---------------------------------------------------------------------------

#define HW 128     // hidden width
#define NBMAX 1024 // max dst buckets (N <= 131072)
#define CAP 4096   // max edges per bucket staged in LDS
#define PBLK 256   // partition blocks (== threads in k_soff2)

typedef _Float16 f16x8 __attribute__((ext_vector_type(8)));
typedef float f32x4 __attribute__((ext_vector_type(4)));

// ---------------- CSR build ----------------
__global__ void k_zero_i32(int* __restrict__ a, int n) {
    int i = blockIdx.x * 256 + threadIdx.x;
    if (i < n) a[i] = 0;
}

// per-block LDS bucket histogram; saves per-block counts + global bucket sums
__global__ __launch_bounds__(256) void k_histb(const int* __restrict__ dstA,
                                               int* __restrict__ bcnt,
                                               int* __restrict__ pcnt,
                                               int nb, int e, int nblk) {
    __shared__ int lh[NBMAX];
    for (int b = threadIdx.x; b < nb; b += 256) lh[b] = 0;
    __syncthreads();
    int blk = blockIdx.x;
    int c0 = (int)(((long long)e * blk) / nblk);
    int c1 = (int)(((long long)e * (blk + 1)) / nblk);
    for (int i = c0 + threadIdx.x; i < c1; i += 256) atomicAdd(&lh[dstA[i] >> 7], 1);
    __syncthreads();
    for (int b = threadIdx.x; b < nb; b += 256) {
        int v = lh[b];
        pcnt[(size_t)blk * nb + b] = v;
        if (v) atomicAdd(&bcnt[b], v);
    }
}

__global__ void k_bscan(const int* __restrict__ bcnt, int* __restrict__ bstart,
                        int nb, int etot) {
    __shared__ int s[1024];
    int t = threadIdx.x;
    int d0 = (t < nb) ? bcnt[t] : 0;
    s[t] = d0;
    __syncthreads();
    for (int off = 1; off < 1024; off <<= 1) {
        int v = (t >= off) ? s[t - off] : 0;
        __syncthreads();
        s[t] += v;
        __syncthreads();
    }
    if (t < nb) bstart[t] = s[t] - d0;
    if (t == 0) bstart[nb] = etot;
}

// per-bucket scan of the PBLK per-block counts -> exact staging offsets
__global__ __launch_bounds__(PBLK) void k_soff2(const int* __restrict__ pcnt,
                                                const int* __restrict__ bstart,
                                                int* __restrict__ soff, int nb) {
    __shared__ int s[PBLK];
    int b = blockIdx.x, t = threadIdx.x;
    int v = pcnt[(size_t)t * nb + b];
    s[t] = v;
    __syncthreads();
    for (int off = 1; off < PBLK; off <<= 1) {
        int u = (t >= off) ? s[t - off] : 0;
        __syncthreads();
        s[t] += u;
        __syncthreads();
    }
    soff[(size_t)t * nb + b] = bstart[b] + s[t] - v;
}

// partition edges into bucket windows using precomputed offsets.
// stage = (src<<7)|(dst&127).
__global__ __launch_bounds__(256) void k_part(const int* __restrict__ srcA,
                                              const int* __restrict__ dstA,
                                              const int* __restrict__ soff,
                                              unsigned* __restrict__ stage,
                                              int nb, int e, int nblk) {
    __shared__ int loff[NBMAX];
    __shared__ int lh[NBMAX];
    int blk = blockIdx.x;
    for (int b = threadIdx.x; b < nb; b += 256) {
        loff[b] = soff[(size_t)blk * nb + b];
        lh[b] = 0;
    }
    __syncthreads();
    int c0 = (int)(((long long)e * blk) / nblk);
    int c1 = (int)(((long long)e * (blk + 1)) / nblk);
    for (int i = c0 + threadIdx.x; i < c1; i += 256) {
        int d = dstA[i];
        int bk = d >> 7;
        int p = loff[bk] + atomicAdd(&lh[bk], 1);
        stage[p] = ((unsigned)srcA[i] << 7) | (unsigned)(d & 127);
    }
}

// one block per bucket: count+scan -> row_start/dis/x4, LDS placement ->
// coalesced csr window write.
__global__ __launch_bounds__(256) void k_build(const unsigned* __restrict__ stage,
                                               const int* __restrict__ bstart,
                                               const float* __restrict__ x,
                                               int* __restrict__ row_start,
                                               float* __restrict__ dis,
                                               float4* __restrict__ x4,
                                               int* __restrict__ csr, int n, int nb) {
    __shared__ int lcnt[128];
    __shared__ int sc[128];
    __shared__ int lcsr[CAP];
    int b = blockIdx.x, tid = threadIdx.x;
    int base = bstart[b], end = bstart[b + 1], cnt = end - base;
    int node0 = b << 7;

    if (tid < 128) lcnt[tid] = 0;
    __syncthreads();
    for (int j = tid; j < cnt; j += 256) atomicAdd(&lcnt[stage[base + j] & 127], 1);
    __syncthreads();
    if (tid < 128) sc[tid] = lcnt[tid];
    __syncthreads();
    for (int off = 1; off < 128; off <<= 1) {
        int v = (tid < 128 && tid >= off) ? sc[tid - off] : 0;
        __syncthreads();
        if (tid < 128) sc[tid] += v;
        __syncthreads();
    }
    int node = node0 + tid;
    if (tid < 128 && node < n) {
        int excl = sc[tid] - lcnt[tid];
        row_start[node] = base + excl;
        float dv = rsqrtf(1.f + (float)lcnt[tid]);
        dis[node] = dv;
        x4[node] = make_float4(x[node * 3] * dv, x[node * 3 + 1] * dv,
                               x[node * 3 + 2] * dv, 0.f);
    }
    if (tid == 0 && b == nb - 1) row_start[n] = end;
    __syncthreads();
    if (tid < 128) sc[tid] = sc[tid] - lcnt[tid];  // exclusive offsets
    if (tid < 128) lcnt[tid] = 0;
    __syncthreads();
    if (cnt <= CAP) {
        for (int j = tid; j < cnt; j += 256) {
            unsigned v = stage[base + j];
            int dl = v & 127;
            int p = atomicAdd(&lcnt[dl], 1);
            lcsr[sc[dl] + p] = (int)(v >> 7);
        }
        __syncthreads();
        for (int j = tid; j < cnt; j += 256) csr[base + j] = lcsr[j];
    } else {
        for (int j = tid; j < cnt; j += 256) {
            unsigned v = stage[base + j];
            int dl = v & 127;
            int p = atomicAdd(&lcnt[dl], 1);
            csr[base + sc[dl] + p] = (int)(v >> 7);
        }
    }
}

// ---------------- W prep: transpose + hi/lo fp16 split ----------------
__global__ void k_prep_wt(const float* __restrict__ Wp, __half* __restrict__ WTh,
                          __half* __restrict__ WTl, int total) {
    int t = blockIdx.x * 256 + threadIdx.x;
    if (t >= total) return;
    int l = t >> 14;
    int kc = t & 16383;
    int k = kc >> 7, c = kc & 127;
    float w = Wp[t];
    __half hi = __float2half_rn(w);
    __half lo = __float2half_rn(w - __half2float(hi));
    size_t o = ((size_t)l << 14) + (size_t)c * HW + k;
    WTh[o] = hi;
    WTl[o] = lo;
}

// ---------------- encoder ----------------
__global__ void k_enc_agg(const float4* __restrict__ x4, const int* __restrict__ rs,
                          const int* __restrict__ csr, const float* __restrict__ dis,
                          float4* __restrict__ zx, int n) {
    int i = blockIdx.x * 256 + threadIdx.x;
    if (i >= n) return;
    float4 a = x4[i];
    int e1 = rs[i + 1];
    for (int j = rs[i]; j < e1; ++j) {
        float4 v = x4[csr[j]];
        a.x += v.x; a.y += v.y; a.z += v.z;
    }
    float d = dis[i];
    zx[i] = make_float4(a.x * d, a.y * d, a.z * d, 0.f);
}

__global__ void k_enc_gemm(const float4* __restrict__ zx, const float* __restrict__ We,
                           const float* __restrict__ be, const float* __restrict__ dis,
                           __half* __restrict__ H, int n) {
    int t = blockIdx.x * 256 + threadIdx.x;
    int i = t >> 7;
    int c = t & 127;
    if (i >= n) return;
    float4 z = zx[i];
    float v = z.x * We[c] + z.y * We[HW + c] + z.z * We[2 * HW + c] + be[c];
    H[(size_t)i * HW + c] = __float2half_rn(fmaxf(v, 0.f) * dis[i]);
}

// ---------------- FUSED layer: agg -> LDS -> MFMA GEMM ----------------------
// 256 threads = 4 waves; block = 16 nodes (one 16-row MFMA tile).
// Phase A (R8 agg): wave owns 4 consecutive nodes, 16 lanes/node, 16B/lane,
//   4-deep unroll; result fp16 -> zs[16][136] (272B row stride, 2-way banks).
// Phase B: wave w computes cols w*32..w*32+32 of relu(Z@W+b)*dis.
//   A-frag: zs[r16][ks*32+q*8]; B-frags from global WTh/WTl (L2-resident).
// mode 1 (last layer): emit t[row] = (relu-row . Wd) instead of H.
__global__ __launch_bounds__(256) void k_layer(const __half* __restrict__ Hin,
                                               const int* __restrict__ rs,
                                               const int* __restrict__ csr,
                                               const float* __restrict__ dis,
                                               const __half* __restrict__ WTh,
                                               const __half* __restrict__ WTl,
                                               const float* __restrict__ b,
                                               __half* __restrict__ Hout,
                                               const float* __restrict__ Wd,
                                               float* __restrict__ tout,
                                               int mode, int n) {
    __shared__ __half zs[16][136];
    __shared__ float psum[4][16];
    int wave = threadIdx.x >> 6, lane = threadIdx.x & 63;
    int lg = lane & 15;   // lane in 16-lane group
    int ln = wave * 4 + (lane >> 4);  // local node 0..15
    int node = blockIdx.x * 16 + ln;
    bool active = node < n;

    // ---- Phase A: aggregate (R8 structure) ----
    float a0[8], a1[8], a2[8], a3[8];
#pragma unroll
    for (int j = 0; j < 8; ++j) { a0[j] = 0.f; a1[j] = 0.f; a2[j] = 0.f; a3[j] = 0.f; }

    int e0 = 0, e1 = 0;
    if (active) {
        e0 = rs[node];
        e1 = rs[node + 1];
        f16x8 hv = *(const f16x8*)(Hin + (size_t)node * HW + lg * 8);
#pragma unroll
        for (int j = 0; j < 8; ++j) a0[j] = (float)hv[j];
    }

    for (int base = e0; base < e1; base += 16) {
        int cnt = e1 - base;
        if (cnt > 16) cnt = 16;
        int sl = (base + lg < e1) ? csr[base + lg] : 0;
        int k = 0;
        for (; k + 4 <= cnt; k += 4) {
            int s0 = __shfl(sl, k + 0, 16);
            int s1 = __shfl(sl, k + 1, 16);
            int s2 = __shfl(sl, k + 2, 16);
            int s3 = __shfl(sl, k + 3, 16);
            f16x8 v0 = *(const f16x8*)(Hin + (size_t)s0 * HW + lg * 8);
            f16x8 v1 = *(const f16x8*)(Hin + (size_t)s1 * HW + lg * 8);
            f16x8 v2 = *(const f16x8*)(Hin + (size_t)s2 * HW + lg * 8);
            f16x8 v3 = *(const f16x8*)(Hin + (size_t)s3 * HW + lg * 8);
#pragma unroll
            for (int j = 0; j < 8; ++j) {
                a0[j] += (float)v0[j];
                a1[j] += (float)v1[j];
                a2[j] += (float)v2[j];
                a3[j] += (float)v3[j];
            }
        }
        for (; k < cnt; ++k) {
            int s = __shfl(sl, k, 16);
            f16x8 v = *(const f16x8*)(Hin + (size_t)s * HW + lg * 8);
#pragma unroll
            for (int j = 0; j < 8; ++j) a0[j] += (float)v[j];
        }
    }

    {
        float d = active ? dis[node] : 0.f;
        union { uint4 u; __half2 h[4]; } pk;
#pragma unroll
        for (int j = 0; j < 4; ++j) {
            float lo = d * ((a0[2 * j] + a1[2 * j]) + (a2[2 * j] + a3[2 * j]));
            float hi = d * ((a0[2 * j + 1] + a1[2 * j + 1]) + (a2[2 * j + 1] + a3[2 * j + 1]));
            pk.h[j] = __floats2half2_rn(lo, hi);
        }
        *(uint4*)&zs[ln][lg * 8] = pk.u;  // inactive rows get zeros
    }
    __syncthreads();

    // ---- Phase B: MFMA GEMM, wave w -> cols w*32..+32 ----
    int q = lane >> 4, r16 = lane & 15;
    f32x4 acc[2];
    acc[0] = (f32x4)0.f;
    acc[1] = (f32x4)0.f;
#pragma unroll
    for (int ks = 0; ks < 4; ++ks) {
        f16x8 afr = *(const f16x8*)&zs[r16][ks * 32 + q * 8];
#pragma unroll
        for (int ntl = 0; ntl < 2; ++ntl) {
            int col = wave * 32 + ntl * 16 + r16;
            f16x8 bh = *(const f16x8*)(WTh + (size_t)col * HW + ks * 32 + q * 8);
            f16x8 bl = *(const f16x8*)(WTl + (size_t)col * HW + ks * 32 + q * 8);
            acc[ntl] = __builtin_amdgcn_mfma_f32_16x16x32_f16(afr, bh, acc[ntl], 0, 0, 0);
            acc[ntl] = __builtin_amdgcn_mfma_f32_16x16x32_f16(afr, bl, acc[ntl], 0, 0, 0);
        }
    }

    int row0 = blockIdx.x * 16;
    if (mode == 0) {
#pragma unroll
        for (int ntl = 0; ntl < 2; ++ntl) {
            int col = wave * 32 + ntl * 16 + r16;
            float bias = b[col];
#pragma unroll
            for (int r = 0; r < 4; ++r) {
                int row = row0 + q * 4 + r;
                if (row < n) {
                    float v = fmaxf(acc[ntl][r] + bias, 0.f) * dis[row];
                    Hout[(size_t)row * HW + col] = __float2half_rn(v);
                }
            }
        }
    } else {
        float pr[4];
#pragma unroll
        for (int r = 0; r < 4; ++r) pr[r] = 0.f;
#pragma unroll
        for (int ntl = 0; ntl < 2; ++ntl) {
            int col = wave * 32 + ntl * 16 + r16;
            float bias = b[col];
            float wd = Wd[col];
#pragma unroll
            for (int r = 0; r < 4; ++r)
                pr[r] += fmaxf(acc[ntl][r] + bias, 0.f) * wd;
        }
#pragma unroll
        for (int r = 0; r < 4; ++r) {
#pragma unroll
            for (int off = 1; off < 16; off <<= 1) pr[r] += __shfl_xor(pr[r], off, 16);
            if (r16 == 0) psum[wave][q * 4 + r] = pr[r];
        }
        __syncthreads();
        if (threadIdx.x < 16) {
            int row = row0 + threadIdx.x;
            if (row < n) {
                float t = (psum[0][threadIdx.x] + psum[1][threadIdx.x]) +
                          (psum[2][threadIdx.x] + psum[3][threadIdx.x]);
                tout[row] = t * dis[row];
            }
        }
    }
}

// ---------------- decoder output ----------------
__global__ void k_dec_out(const float* __restrict__ t, const int* __restrict__ rs,
                          const int* __restrict__ csr, const float* __restrict__ dis,
                          const float* __restrict__ bdec, const float* __restrict__ mask,
                          float* __restrict__ out, int n) {
    int i = blockIdx.x * 256 + threadIdx.x;
    if (i >= n) return;
    float acc = t[i];
    int e1 = rs[i + 1];
    for (int j = rs[i]; j < e1; ++j) acc += t[csr[j]];
    out[i] = (dis[i] * acc + bdec[0]) * mask[i];
}

// ---------------------------------------------------------------------------
static inline size_t align256(size_t x) { return (x + 255) & ~(size_t)255; }

extern "C" void kernel_launch(void* const* d_in, const int* in_sizes, int n_in,
                              void* d_out, int out_size, void* d_ws, size_t ws_size,
                              hipStream_t stream) {
    const float* x     = (const float*)d_in[0];
    const float* mask  = (const float*)d_in[1];
    const int*   ei    = (const int*)d_in[2];
    const float* W_enc = (const float*)d_in[3];
    const float* b_enc = (const float*)d_in[4];
    const float* W_p   = (const float*)d_in[5];
    const float* b_p   = (const float*)d_in[6];
    const float* W_dec = (const float*)d_in[7];
    const float* b_dec = (const float*)d_in[8];

    const int N = in_sizes[1];
    const int E = in_sizes[2] / 2;
    const int* srcA = ei;
    const int* dstA = ei + E;
    const int NB = (N + 127) >> 7;  // dst buckets of 128 nodes (<= NBMAX)

    char* p = (char*)d_ws;
    size_t off = 0;
    auto carve = [&](size_t bytes) {
        void* r = p + off;
        off += align256(bytes);
        return r;
    };
    int*      bcnt      = (int*)carve((size_t)NB * 4);
    int*      bstart    = (int*)carve((size_t)(NB + 1) * 4);
    int*      pcnt      = (int*)carve((size_t)PBLK * NB * 4);
    int*      soff      = (int*)carve((size_t)PBLK * NB * 4);
    int*      row_start = (int*)carve((size_t)(N + 1) * 4);
    unsigned* stage     = (unsigned*)carve((size_t)E * 4);
    int*      csr       = (int*)carve((size_t)E * 4);
    float*    dis       = (float*)carve((size_t)N * 4);
    float4*   x4        = (float4*)carve((size_t)N * 16);
    float4*   zx        = (float4*)carve((size_t)N * 16);
    float*    tdec      = (float*)carve((size_t)N * 4);
    __half*   WTh       = (__half*)carve((size_t)4 * HW * HW * 2);
    __half*   WTl       = (__half*)carve((size_t)4 * HW * HW * 2);
    __half*   HA        = (__half*)carve((size_t)N * HW * 2);
    __half*   HB        = (__half*)carve((size_t)N * HW * 2);

    const int gN   = (N + 255) / 256;
    const int gL   = (N + 15) / 16;
    const int WPT  = 4 * HW * HW;

    // ---- CSR build (LDS-radix, no re-hist) + preps ----
    k_zero_i32<<<(NB + 255) / 256, 256, 0, stream>>>(bcnt, NB);
    k_histb<<<PBLK, 256, 0, stream>>>(dstA, bcnt, pcnt, NB, E, PBLK);
    k_bscan<<<1, 1024, 0, stream>>>(bcnt, bstart, NB, E);
    k_soff2<<<NB, PBLK, 0, stream>>>(pcnt, bstart, soff, NB);
    k_part<<<PBLK, 256, 0, stream>>>(srcA, dstA, soff, stage, NB, E, PBLK);
    k_build<<<NB, 256, 0, stream>>>(stage, bstart, x, row_start, dis, x4, csr, N, NB);
    k_prep_wt<<<(WPT + 255) / 256, 256, 0, stream>>>(W_p, WTh, WTl, WPT);

    // ---- encoder ----
    k_enc_agg<<<gN, 256, 0, stream>>>(x4, row_start, csr, dis, zx, N);
    k_enc_gemm<<<(N * HW + 255) / 256, 256, 0, stream>>>(zx, W_enc, b_enc, dis, HA, N);

    // ---- 4 fused processor layers (ping-pong HA/HB; no Z buffer) ----
    __half* Hin = HA;
    __half* Hout = HB;
    for (int l = 0; l < 4; ++l) {
        int mode = (l == 3) ? 1 : 0;
        k_layer<<<gL, 256, 0, stream>>>(Hin, row_start, csr, dis,
                                        WTh + (size_t)l * HW * HW,
                                        WTl + (size_t)l * HW * HW,
                                        b_p + (size_t)l * HW, Hout,
                                        W_dec, tdec, mode, N);
        __half* t = Hin; Hin = Hout; Hout = t;
    }

    // ---- decoder output ----
    k_dec_out<<<gN, 256, 0, stream>>>(tdec, row_start, csr, dis, b_dec, mask,
                                      (float*)d_out, N);
}